// Round 1
// baseline (14757.835 us; speedup 1.0000x reference)
//
#include <hip/hip_runtime.h>
#include <math.h>

// SCNN fused network, fp32, one workgroup (128 threads) per batch element.
// All activations live in LDS; skip tensors e1/e2/e3 kept in LDS; no d_ws use.

#define CS 49  // LDS row stride in floats; 49 is coprime with 32 banks -> conflict-free row-strided access

__device__ __forceinline__ int l_of(int c) {
  // degree groups: c=0 -> l0; 1..5 -> l1; 6..14 -> l2; 15..27 -> l3; 28..44 -> l4
  return (c >= 1) + (c >= 6) + (c >= 15) + (c >= 28);
}

__device__ __forceinline__ float lfac_of(int l) {
  // sqrt(pi / (2*degree+1)), degree = 2l
  return sqrtf(3.14159265358979323846f / (float)(4 * l + 1));
}

// Compute out[o, c] for c in [CB, CE): out = lfac(c) * sum_i w[o,i,l(c)] * in[i,c]
// Input rows: rows [0,SPLIT) from inA, rows [SPLIT,I) from inB (concat support).
template <int I, int SPLIT, int CB, int CE>
__device__ __forceinline__ void sconv_cols(const float* __restrict__ w, int o,
                                           const float* inA, const float* inB,
                                           float* outRow) {
  constexpr int NCB = CE - CB;
  float acc[NCB];
#pragma unroll
  for (int k = 0; k < NCB; ++k) acc[k] = 0.f;
  const float* __restrict__ wo = w + o * (I * 5);
#pragma unroll 2
  for (int i = 0; i < SPLIT; ++i) {
    const float* xi = inA + i * CS;
    const float* __restrict__ wi = wo + i * 5;
    const float wv0 = wi[0], wv1 = wi[1], wv2 = wi[2], wv3 = wi[3], wv4 = wi[4];
#pragma unroll
    for (int k = 0; k < NCB; ++k) {
      const int c = CB + k;
      const int l = l_of(c);
      const float wv = (l == 0) ? wv0 : (l == 1) ? wv1 : (l == 2) ? wv2 : (l == 3) ? wv3 : wv4;
      acc[k] += wv * xi[c];
    }
  }
  if constexpr (SPLIT < I) {
#pragma unroll 2
    for (int i = SPLIT; i < I; ++i) {
      const float* xi = inB + (i - SPLIT) * CS;
      const float* __restrict__ wi = wo + i * 5;
      const float wv0 = wi[0], wv1 = wi[1], wv2 = wi[2], wv3 = wi[3], wv4 = wi[4];
#pragma unroll
      for (int k = 0; k < NCB; ++k) {
        const int c = CB + k;
        const int l = l_of(c);
        const float wv = (l == 0) ? wv0 : (l == 1) ? wv1 : (l == 2) ? wv2 : (l == 3) ? wv3 : wv4;
        acc[k] += wv * xi[c];
      }
    }
  }
#pragma unroll
  for (int k = 0; k < NCB; ++k) {
    const int c = CB + k;
    outRow[c] = acc[k] * lfac_of(l_of(c));
  }
}

// Map 128 threads onto O output rows x 45 cols with compile-time c-ranges.
template <int O, int I, int SPLIT>
__device__ __forceinline__ void sconv_layer(const float* __restrict__ w,
                                            const float* inA, const float* inB,
                                            float* out, int tid) {
  if constexpr (O == 128) {
    sconv_cols<I, SPLIT, 0, 45>(w, tid, inA, inB, out + tid * CS);
  } else if constexpr (O == 64) {
    const int o = tid & 63;
    if (tid < 64) sconv_cols<I, SPLIT, 0, 23>(w, o, inA, inB, out + o * CS);
    else          sconv_cols<I, SPLIT, 23, 45>(w, o, inA, inB, out + o * CS);
  } else if constexpr (O == 32) {
    const int o = tid & 31;
    switch (tid >> 5) {
      case 0:  sconv_cols<I, SPLIT, 0, 12>(w, o, inA, inB, out + o * CS); break;
      case 1:  sconv_cols<I, SPLIT, 12, 24>(w, o, inA, inB, out + o * CS); break;
      case 2:  sconv_cols<I, SPLIT, 24, 35>(w, o, inA, inB, out + o * CS); break;
      default: sconv_cols<I, SPLIT, 35, 45>(w, o, inA, inB, out + o * CS); break;
    }
  } else {  // O == 16
    const int o = tid & 15;
    switch (tid >> 4) {
      case 0:  sconv_cols<I, SPLIT, 0, 6>(w, o, inA, inB, out + o * CS); break;
      case 1:  sconv_cols<I, SPLIT, 6, 12>(w, o, inA, inB, out + o * CS); break;
      case 2:  sconv_cols<I, SPLIT, 12, 18>(w, o, inA, inB, out + o * CS); break;
      case 3:  sconv_cols<I, SPLIT, 18, 24>(w, o, inA, inB, out + o * CS); break;
      case 4:  sconv_cols<I, SPLIT, 24, 30>(w, o, inA, inB, out + o * CS); break;
      case 5:  sconv_cols<I, SPLIT, 30, 35>(w, o, inA, inB, out + o * CS); break;
      case 6:  sconv_cols<I, SPLIT, 35, 40>(w, o, inA, inB, out + o * CS); break;
      default: sconv_cols<I, SPLIT, 40, 45>(w, o, inA, inB, out + o * CS); break;
    }
  }
}

// nonlin: out[i,c] = sum_d sft[c,d] * relu(sum_c' isft[d,c'] * in[i,c'])
// Rows [0,SPLITI) from inA/outA, rows [SPLITI,I) from inB/outB (concat, in-place safe).
// I==128: 1 thread per row. I<128: two waves split the d-dimension (50 each), merge via LDS.
template <int I, int SPLITI>
__device__ void nonlin_layer(const float* __restrict__ isft, const float* __restrict__ sft,
                             const float* inA, const float* inB,
                             float* outA, float* outB,
                             float* red, int tid) {
  constexpr int P = (I == 128) ? 1 : 2;
  constexpr int DCNT = (P == 1) ? 100 : 50;
  const int r = (P == 1) ? tid : (tid & 63);
  const int s = (P == 1) ? 0 : (tid >> 6);
  int dBeg = 0;
  if constexpr (P == 2) dBeg = __builtin_amdgcn_readfirstlane(s * 50);  // wave-uniform -> scalar loads
  const bool act = (r < I);

  float xr[45];
  float oc[45];
  if (act) {
    const float* inRow = (r < SPLITI) ? (inA + r * CS) : (inB + (r - SPLITI) * CS);
#pragma unroll
    for (int c = 0; c < 45; ++c) xr[c] = inRow[c];
#pragma unroll
    for (int c = 0; c < 45; ++c) oc[c] = 0.f;
#pragma unroll 2
    for (int dd = 0; dd < DCNT; ++dd) {
      const int d = dBeg + dd;
      const float* __restrict__ ir = isft + d * 45;
      float y0 = 0.f, y1 = 0.f, y2 = 0.f, y3 = 0.f;
#pragma unroll
      for (int c = 0; c + 3 < 45; c += 4) {
        y0 += ir[c] * xr[c];
        y1 += ir[c + 1] * xr[c + 1];
        y2 += ir[c + 2] * xr[c + 2];
        y3 += ir[c + 3] * xr[c + 3];
      }
      y0 += ir[44] * xr[44];
      float y = (y0 + y1) + (y2 + y3);
      y = fmaxf(y, 0.f);
#pragma unroll
      for (int c = 0; c < 45; ++c) oc[c] += sft[c * 100 + d] * y;
    }
  }
  if constexpr (P == 2) {
    if (act && s == 1) {
#pragma unroll
      for (int c = 0; c < 45; ++c) red[r * CS + c] = oc[c];
    }
    __syncthreads();
    if (act && s == 0) {
#pragma unroll
      for (int c = 0; c < 45; ++c) oc[c] += red[r * CS + c];
    }
  }
  if (act && s == 0) {
    float* outRow = (r < SPLITI) ? (outA + r * CS) : (outB + (r - SPLITI) * CS);
#pragma unroll
    for (int c = 0; c < 45; ++c) outRow[c] = oc[c];
  }
}

__global__ __launch_bounds__(128) void scnn_fused(
    const float* __restrict__ x, const float* __restrict__ sft, const float* __restrict__ isft,
    const float* __restrict__ w1, const float* __restrict__ w2, const float* __restrict__ w3,
    const float* __restrict__ w4, const float* __restrict__ w5, const float* __restrict__ w6,
    const float* __restrict__ w7, const float* __restrict__ w8, const float* __restrict__ w9,
    float* __restrict__ out) {
  __shared__ float bufP[128 * CS];
  __shared__ float bufQ[64 * CS];
  __shared__ float e1b[16 * CS];
  __shared__ float e2b[32 * CS];
  __shared__ float e3b[64 * CS];
  __shared__ float redb[64 * CS];

  const int tid = threadIdx.x;
  const int b = blockIdx.x;

  // stage x [4,45] into bufQ rows 0..3
  for (int idx = tid; idx < 180; idx += 128)
    bufQ[(idx / 45) * CS + (idx % 45)] = x[b * 180 + idx];
  __syncthreads();

  sconv_layer<16, 4, 4>(w1, bufQ, bufQ, bufP, tid);
  __syncthreads();
  nonlin_layer<16, 16>(isft, sft, bufP, bufP, e1b, e1b, redb, tid);  // e1
  __syncthreads();
  sconv_layer<32, 16, 16>(w2, e1b, e1b, bufP, tid);
  __syncthreads();
  nonlin_layer<32, 32>(isft, sft, bufP, bufP, e2b, e2b, redb, tid);  // e2
  __syncthreads();
  sconv_layer<64, 32, 32>(w3, e2b, e2b, bufP, tid);
  __syncthreads();
  nonlin_layer<64, 64>(isft, sft, bufP, bufP, e3b, e3b, redb, tid);  // e3
  __syncthreads();
  sconv_layer<128, 64, 64>(w4, e3b, e3b, bufP, tid);
  __syncthreads();
  nonlin_layer<128, 128>(isft, sft, bufP, bufP, bufP, bufP, redb, tid);  // e4 (in place)
  __syncthreads();
  sconv_layer<64, 128, 128>(w5, bufP, bufP, bufQ, tid);  // F = sconv(e4,w5) -> bufQ[0..63]
  __syncthreads();
  nonlin_layer<128, 64>(isft, sft, bufQ, e3b, bufQ, e3b, redb, tid);  // d1 = nonlin([F; e3]) in place
  __syncthreads();
  sconv_layer<32, 128, 64>(w6, bufQ, e3b, bufP, tid);  // G -> bufP[0..31]
  __syncthreads();
  nonlin_layer<64, 32>(isft, sft, bufP, e2b, bufP, e2b, redb, tid);  // d2 = nonlin([G; e2]) in place
  __syncthreads();
  sconv_layer<16, 64, 32>(w7, bufP, e2b, bufQ, tid);  // H -> bufQ[0..15]
  __syncthreads();
  nonlin_layer<32, 16>(isft, sft, bufQ, e1b, bufQ, e1b, redb, tid);  // d3 = nonlin([H; e1]) in place
  __syncthreads();
  sconv_layer<16, 32, 16>(w8, bufQ, e1b, bufP, tid);  // -> bufP[0..15]
  __syncthreads();
  nonlin_layer<16, 16>(isft, sft, bufP, bufP, bufP, bufP, redb, tid);  // d4 (in place)
  __syncthreads();

  // final sconv: O=1, I=16 -> out[b, c]
  if (tid < 45) {
    const int c = tid;
    const int l = l_of(c);
    float acc = 0.f;
#pragma unroll
    for (int i = 0; i < 16; ++i) acc += w9[i * 5 + l] * bufP[i * CS + c];
    out[b * 45 + c] = acc * lfac_of(l);
  }
}

extern "C" void kernel_launch(void* const* d_in, const int* in_sizes, int n_in,
                              void* d_out, int out_size, void* d_ws, size_t ws_size,
                              hipStream_t stream) {
  (void)d_ws; (void)ws_size; (void)n_in;
  const float* x    = (const float*)d_in[0];
  const float* sft  = (const float*)d_in[1];
  const float* isft = (const float*)d_in[2];
  const float* w1 = (const float*)d_in[3];
  const float* w2 = (const float*)d_in[4];
  const float* w3 = (const float*)d_in[5];
  const float* w4 = (const float*)d_in[6];
  const float* w5 = (const float*)d_in[7];
  const float* w6 = (const float*)d_in[8];
  const float* w7 = (const float*)d_in[9];
  const float* w8 = (const float*)d_in[10];
  const float* w9 = (const float*)d_in[11];
  float* out = (float*)d_out;

  const int batch = in_sizes[0] / (4 * 45);  // 16384
  hipLaunchKernelGGL(scnn_fused, dim3(batch), dim3(128), 0, stream,
                     x, sft, isft, w1, w2, w3, w4, w5, w6, w7, w8, w9, out);
}

// Round 2
// 7799.314 us; speedup vs baseline: 1.8922x; 1.8922x over previous
//
#include <hip/hip_runtime.h>
#include <math.h>

// SCNN fused network, fp32, one workgroup (128 threads) per batch element.
// Round 2: LDS 72KB -> 43.2KB (3 blocks/CU), sft pre-transposed into d_ws so
// nonlin's scalar loads are contiguous (s_load_dwordx16 instead of 45x s_load_dword).

#define CS 45  // odd stride -> row-strided lane access is 2-lanes/bank = conflict-free

__device__ __forceinline__ int l_of(int c) {
  // degree groups: c=0 -> l0; 1..5 -> l1; 6..14 -> l2; 15..27 -> l3; 28..44 -> l4
  return (c >= 1) + (c >= 6) + (c >= 15) + (c >= 28);
}

__device__ __forceinline__ float lfac_of(int l) {
  // sqrt(pi / (2*degree+1)), degree = 2l
  return sqrtf(3.14159265358979323846f / (float)(4 * l + 1));
}

// out[o, c] for c in [CB, CE): out = lfac(c) * sum_i w[o,i,l(c)] * in[i,c]
// Rows [0,SPLIT) from inA, rows [SPLIT,I) from inB (concat support).
template <int I, int SPLIT, int CB, int CE>
__device__ __forceinline__ void sconv_cols(const float* __restrict__ w, int o,
                                           const float* inA, const float* inB,
                                           float* outRow) {
  constexpr int NCB = CE - CB;
  float acc[NCB];
#pragma unroll
  for (int k = 0; k < NCB; ++k) acc[k] = 0.f;
  const float* __restrict__ wo = w + o * (I * 5);
#pragma unroll 2
  for (int i = 0; i < SPLIT; ++i) {
    const float* xi = inA + i * CS;
    const float* __restrict__ wi = wo + i * 5;
    const float wv0 = wi[0], wv1 = wi[1], wv2 = wi[2], wv3 = wi[3], wv4 = wi[4];
#pragma unroll
    for (int k = 0; k < NCB; ++k) {
      const int c = CB + k;
      const int l = l_of(c);
      const float wv = (l == 0) ? wv0 : (l == 1) ? wv1 : (l == 2) ? wv2 : (l == 3) ? wv3 : wv4;
      acc[k] += wv * xi[c];
    }
  }
  if constexpr (SPLIT < I) {
#pragma unroll 2
    for (int i = SPLIT; i < I; ++i) {
      const float* xi = inB + (i - SPLIT) * CS;
      const float* __restrict__ wi = wo + i * 5;
      const float wv0 = wi[0], wv1 = wi[1], wv2 = wi[2], wv3 = wi[3], wv4 = wi[4];
#pragma unroll
      for (int k = 0; k < NCB; ++k) {
        const int c = CB + k;
        const int l = l_of(c);
        const float wv = (l == 0) ? wv0 : (l == 1) ? wv1 : (l == 2) ? wv2 : (l == 3) ? wv3 : wv4;
        acc[k] += wv * xi[c];
      }
    }
  }
#pragma unroll
  for (int k = 0; k < NCB; ++k) {
    const int c = CB + k;
    outRow[c] = acc[k] * lfac_of(l_of(c));
  }
}

// Map 128 threads onto O output rows x 45 cols with compile-time c-ranges.
template <int O, int I, int SPLIT>
__device__ __forceinline__ void sconv_layer(const float* __restrict__ w,
                                            const float* inA, const float* inB,
                                            float* out, int tid) {
  if constexpr (O == 128) {
    sconv_cols<I, SPLIT, 0, 45>(w, tid, inA, inB, out + tid * CS);
  } else if constexpr (O == 64) {
    const int o = tid & 63;
    if (tid < 64) sconv_cols<I, SPLIT, 0, 23>(w, o, inA, inB, out + o * CS);
    else          sconv_cols<I, SPLIT, 23, 45>(w, o, inA, inB, out + o * CS);
  } else if constexpr (O == 32) {
    const int o = tid & 31;
    switch (tid >> 5) {
      case 0:  sconv_cols<I, SPLIT, 0, 12>(w, o, inA, inB, out + o * CS); break;
      case 1:  sconv_cols<I, SPLIT, 12, 24>(w, o, inA, inB, out + o * CS); break;
      case 2:  sconv_cols<I, SPLIT, 24, 35>(w, o, inA, inB, out + o * CS); break;
      default: sconv_cols<I, SPLIT, 35, 45>(w, o, inA, inB, out + o * CS); break;
    }
  } else {  // O == 16
    const int o = tid & 15;
    switch (tid >> 4) {
      case 0:  sconv_cols<I, SPLIT, 0, 6>(w, o, inA, inB, out + o * CS); break;
      case 1:  sconv_cols<I, SPLIT, 6, 12>(w, o, inA, inB, out + o * CS); break;
      case 2:  sconv_cols<I, SPLIT, 12, 18>(w, o, inA, inB, out + o * CS); break;
      case 3:  sconv_cols<I, SPLIT, 18, 24>(w, o, inA, inB, out + o * CS); break;
      case 4:  sconv_cols<I, SPLIT, 24, 30>(w, o, inA, inB, out + o * CS); break;
      case 5:  sconv_cols<I, SPLIT, 30, 35>(w, o, inA, inB, out + o * CS); break;
      case 6:  sconv_cols<I, SPLIT, 35, 40>(w, o, inA, inB, out + o * CS); break;
      default: sconv_cols<I, SPLIT, 40, 45>(w, o, inA, inB, out + o * CS); break;
    }
  }
}

// Register-accumulating sconv for w5 (O=64, I=128): result stays in regs so the
// output can overwrite the input buffer after a sync (no bufQ needed).
template <int CB, int CE>
__device__ __forceinline__ void sconv_reg(const float* __restrict__ w, int o,
                                          const float* in, float* acc) {
  constexpr int N = CE - CB;
#pragma unroll
  for (int k = 0; k < N; ++k) acc[k] = 0.f;
  const float* __restrict__ wo = w + o * (128 * 5);
#pragma unroll 2
  for (int i = 0; i < 128; ++i) {
    const float* xi = in + i * CS;
    const float* __restrict__ wi = wo + i * 5;
    const float wv0 = wi[0], wv1 = wi[1], wv2 = wi[2], wv3 = wi[3], wv4 = wi[4];
#pragma unroll
    for (int k = 0; k < N; ++k) {
      const int c = CB + k;
      const int l = l_of(c);
      const float wv = (l == 0) ? wv0 : (l == 1) ? wv1 : (l == 2) ? wv2 : (l == 3) ? wv3 : wv4;
      acc[k] += wv * xi[c];
    }
  }
#pragma unroll
  for (int k = 0; k < N; ++k) acc[k] *= lfac_of(l_of(CB + k));
}

// nonlin: out[i,c] = sum_d sftT[d,c] * relu(sum_c' isft[d,c'] * in[i,c'])
// Rows [0,SPLITI) from inA/outA, rows [SPLITI,I) from inB/outB (concat, in-place safe).
// I==128: 1 thread per row. I<128: two waves split the d-dimension (50 each), merge via red.
template <int I, int SPLITI, bool TR>
__device__ void nonlin_layer(const float* __restrict__ isft, const float* __restrict__ sf,
                             const float* inA, const float* inB,
                             float* outA, float* outB,
                             float* red, int tid) {
  constexpr int P = (I == 128) ? 1 : 2;
  constexpr int DCNT = (P == 1) ? 100 : 50;
  const int r = (P == 1) ? tid : (tid & 63);
  const int s = (P == 1) ? 0 : (tid >> 6);
  int dBeg = 0;
  if constexpr (P == 2) dBeg = __builtin_amdgcn_readfirstlane(s * 50);  // wave-uniform -> scalar loads
  const bool act = (r < I);

  float xr[45];
  float oc[45];
  if (act) {
    const float* inRow = (r < SPLITI) ? (inA + r * CS) : (inB + (r - SPLITI) * CS);
#pragma unroll
    for (int c = 0; c < 45; ++c) xr[c] = inRow[c];
#pragma unroll
    for (int c = 0; c < 45; ++c) oc[c] = 0.f;
#pragma unroll 2
    for (int dd = 0; dd < DCNT; ++dd) {
      const int d = dBeg + dd;
      const float* __restrict__ ir = isft + d * 45;
      float y0 = 0.f, y1 = 0.f, y2 = 0.f, y3 = 0.f;
#pragma unroll
      for (int c = 0; c + 3 < 45; c += 4) {
        y0 += ir[c] * xr[c];
        y1 += ir[c + 1] * xr[c + 1];
        y2 += ir[c + 2] * xr[c + 2];
        y3 += ir[c + 3] * xr[c + 3];
      }
      y0 += ir[44] * xr[44];
      float y = fmaxf((y0 + y1) + (y2 + y3), 0.f);
      if constexpr (TR) {
        const float* __restrict__ sr = sf + d * 45;  // contiguous row -> s_load_dwordx16
#pragma unroll
        for (int c = 0; c < 45; ++c) oc[c] += sr[c] * y;
      } else {
#pragma unroll
        for (int c = 0; c < 45; ++c) oc[c] += sf[c * 100 + d] * y;
      }
    }
  }
  if constexpr (P == 2) {
    if (act && s == 1) {
#pragma unroll
      for (int c = 0; c < 45; ++c) red[r * CS + c] = oc[c];
    }
    __syncthreads();
    if (act && s == 0) {
#pragma unroll
      for (int c = 0; c < 45; ++c) oc[c] += red[r * CS + c];
    }
  }
  if (act && s == 0) {
    float* outRow = (r < SPLITI) ? (outA + r * CS) : (outB + (r - SPLITI) * CS);
#pragma unroll
    for (int c = 0; c < 45; ++c) outRow[c] = oc[c];
  }
}

template <bool TR>
__global__ __launch_bounds__(128) void scnn_fused(
    const float* __restrict__ x, const float* __restrict__ sf, const float* __restrict__ isft,
    const float* __restrict__ w1, const float* __restrict__ w2, const float* __restrict__ w3,
    const float* __restrict__ w4, const float* __restrict__ w5, const float* __restrict__ w6,
    const float* __restrict__ w7, const float* __restrict__ w8, const float* __restrict__ w9,
    float* __restrict__ out) {
  __shared__ float bufP[128 * CS];  // main buffer; also hosts `red` overlays in dead rows
  __shared__ float e1b[16 * CS];
  __shared__ float e2b[32 * CS];
  __shared__ float e3b[64 * CS];
  // total: 240 rows * 45 * 4B = 43,200 B -> 3 blocks/CU

  const int tid = threadIdx.x;
  const int b = blockIdx.x;

  // stage x [4,45] into e3b rows 0..3 (CS==45 -> flat copy)
  for (int idx = tid; idx < 180; idx += 128) e3b[idx] = x[b * 180 + idx];
  __syncthreads();

  sconv_layer<16, 4, 4>(w1, e3b, e3b, bufP, tid);                       // t1 -> bufP[0..15]
  __syncthreads();
  nonlin_layer<16, 16, TR>(isft, sf, bufP, bufP, e1b, e1b, bufP + 16 * CS, tid);   // e1
  __syncthreads();
  sconv_layer<32, 16, 16>(w2, e1b, e1b, bufP, tid);                     // t2 -> bufP[0..31]
  __syncthreads();
  nonlin_layer<32, 32, TR>(isft, sf, bufP, bufP, e2b, e2b, bufP + 32 * CS, tid);   // e2
  __syncthreads();
  sconv_layer<64, 32, 32>(w3, e2b, e2b, bufP, tid);                     // t3 -> bufP[0..63]
  __syncthreads();
  nonlin_layer<64, 64, TR>(isft, sf, bufP, bufP, e3b, e3b, bufP + 64 * CS, tid);   // e3 (x dead)
  __syncthreads();
  sconv_layer<128, 64, 64>(w4, e3b, e3b, bufP, tid);                    // t4 -> bufP[0..127]
  __syncthreads();
  nonlin_layer<128, 128, TR>(isft, sf, bufP, bufP, bufP, bufP, nullptr, tid);      // e4 in place
  __syncthreads();

  // F = sconv(e4, w5): register-staged, then overwrite bufP rows 0..63
  {
    float facc[23];
    const int o = tid & 63;
    if (tid < 64) sconv_reg<0, 23>(w5, o, bufP, facc);
    else          sconv_reg<23, 45>(w5, o, bufP, facc);
    __syncthreads();
    if (tid < 64) {
#pragma unroll
      for (int k = 0; k < 23; ++k) bufP[o * CS + k] = facc[k];
    } else {
#pragma unroll
      for (int k = 0; k < 22; ++k) bufP[o * CS + 23 + k] = facc[k];
    }
  }
  __syncthreads();
  nonlin_layer<128, 64, TR>(isft, sf, bufP, e3b, bufP, e3b, nullptr, tid);         // d1 in place
  __syncthreads();
  sconv_layer<32, 128, 64>(w6, bufP, e3b, bufP + 64 * CS, tid);         // G -> bufP[64..95]
  __syncthreads();
  nonlin_layer<64, 32, TR>(isft, sf, bufP + 64 * CS, e2b, bufP + 64 * CS, e2b, bufP, tid);  // d2
  __syncthreads();
  sconv_layer<16, 64, 32>(w7, bufP + 64 * CS, e2b, bufP, tid);          // H -> bufP[0..15]
  __syncthreads();
  nonlin_layer<32, 16, TR>(isft, sf, bufP, e1b, bufP, e1b, bufP + 16 * CS, tid);   // d3
  __syncthreads();
  sconv_layer<16, 32, 16>(w8, bufP, e1b, bufP + 16 * CS, tid);          // t8 -> bufP[16..31]
  __syncthreads();
  nonlin_layer<16, 16, TR>(isft, sf, bufP + 16 * CS, bufP + 16 * CS,
                           bufP + 16 * CS, bufP + 16 * CS, bufP + 32 * CS, tid);   // d4
  __syncthreads();

  // final sconv: O=1, I=16 (d4 at rows 16..31) -> out[b, c]
  if (tid < 45) {
    const int c = tid;
    const int l = l_of(c);
    float acc = 0.f;
#pragma unroll
    for (int i = 0; i < 16; ++i) acc += w9[i * 5 + l] * bufP[(16 + i) * CS + c];
    out[b * 45 + c] = acc * lfac_of(l);
  }
}

__global__ void sft_transpose_k(const float* __restrict__ sft, float* __restrict__ sftT) {
  const int idx = blockIdx.x * 256 + threadIdx.x;
  if (idx < 4500) {
    const int d = idx / 45, c = idx % 45;
    sftT[idx] = sft[c * 100 + d];
  }
}

extern "C" void kernel_launch(void* const* d_in, const int* in_sizes, int n_in,
                              void* d_out, int out_size, void* d_ws, size_t ws_size,
                              hipStream_t stream) {
  (void)n_in; (void)out_size;
  const float* x    = (const float*)d_in[0];
  const float* sft  = (const float*)d_in[1];
  const float* isft = (const float*)d_in[2];
  const float* w1 = (const float*)d_in[3];
  const float* w2 = (const float*)d_in[4];
  const float* w3 = (const float*)d_in[5];
  const float* w4 = (const float*)d_in[6];
  const float* w5 = (const float*)d_in[7];
  const float* w6 = (const float*)d_in[8];
  const float* w7 = (const float*)d_in[9];
  const float* w8 = (const float*)d_in[10];
  const float* w9 = (const float*)d_in[11];
  float* out = (float*)d_out;

  const int batch = in_sizes[0] / (4 * 45);  // 16384

  if (ws_size >= 4500 * sizeof(float)) {
    float* sftT = (float*)d_ws;
    hipLaunchKernelGGL(sft_transpose_k, dim3(18), dim3(256), 0, stream, sft, sftT);
    hipLaunchKernelGGL((scnn_fused<true>), dim3(batch), dim3(128), 0, stream,
                       x, sftT, isft, w1, w2, w3, w4, w5, w6, w7, w8, w9, out);
  } else {
    hipLaunchKernelGGL((scnn_fused<false>), dim3(batch), dim3(128), 0, stream,
                       x, sft, isft, w1, w2, w3, w4, w5, w6, w7, w8, w9, out);
  }
}

// Round 4
// 2853.438 us; speedup vs baseline: 5.1719x; 2.7333x over previous
//
#include <hip/hip_runtime.h>
#include <math.h>

// SCNN fused, round 4: round-3 design with the cvt_pkrtz return-type fix.
// nonlin via fp16 MFMA (16x16x32), sconv via VALU fp32 with transposed weights.
// One workgroup (256 thr) per batch element. Activations fp16 in LDS.

typedef _Float16 half_t;
typedef _Float16 f16x8 __attribute__((ext_vector_type(8)));
typedef float f32x4 __attribute__((ext_vector_type(4)));
typedef unsigned int u32;

#define ROWB 144   // bytes per LDS row: 48 fp16 data + 16 fp16 zero-pad + 8 slack
#define NROWS 240
#define E1R 128
#define E2R 144
#define E3R 176

// ws layout (u32 units): [0,3584) A1 frags, [3584,6656) A2 frags, then wT floats
#define WS_FRAG_U32 6656
#define WT_FLOATS 123280
#define WS_NEEDED ((WS_FRAG_U32 + WT_FLOATS) * 4)

__device__ __host__ __forceinline__ constexpr int l_of(int c) {
  return (c >= 1) + (c >= 6) + (c >= 15) + (c >= 28);
}
__device__ __forceinline__ float lfac_of(int l) {
  return sqrtf(3.14159265358979323846f / (float)(4 * l + 1));
}

// pack two fp32 -> one u32 holding two fp16 (RTZ)
__device__ __forceinline__ u32 pk2(float a, float b) {
  auto v = __builtin_amdgcn_cvt_pkrtz(a, b);  // __fp16 ext_vector(2)
  return __builtin_bit_cast(u32, v);
}

__device__ __forceinline__ f32x4 mfma16(f16x8 a, f16x8 b, f32x4 c) {
  return __builtin_amdgcn_mfma_f32_16x16x32_f16(a, b, c, 0, 0, 0);
}

struct Frags {
  f16x8 a1[7][2];  // isft: d = 16*mt + (l&15), c = 32*kt + 8*(l>>4) + j  (0 if d>=100||c>=45)
  f16x8 a2[3][4];  // sft:  c = 16*mt + (l&15), d = 32*kt + 8*(l>>4) + j  (0 if c>=45||d>=100)
};

// ---------------- nonlin: out[r,c] = sum_d sft[c,d] * relu(sum_c' isft[d,c'] in[r,c'])
// Wave-level, one 16-row tile per iteration; tiles split across 4 waves.
__device__ void nonlin_tiles(const Frags& F, char* smem, int lane, int wid,
                             int T, int TA, int inArow, int inBrow,
                             int outArow, int outBrow) {
  const int i15 = lane & 15, g = lane >> 4;
  for (int t = wid; t < T; t += 4) {
    const int inrow = (t < TA) ? (inArow + t * 16) : (inBrow + (t - TA) * 16);
    const int outrow = (t < TA) ? (outArow + t * 16) : (outBrow + (t - TA) * 16);
    const char* ib = smem + (inrow + i15) * ROWB + g * 16;
    f16x8 b0 = *(const f16x8*)(ib);        // c = 8g + j
    f16x8 b1 = *(const f16x8*)(ib + 64);   // c = 32 + 8g + j
    f32x4 acc1[7];
#pragma unroll
    for (int mt = 0; mt < 7; ++mt) {
      f32x4 z = {0.f, 0.f, 0.f, 0.f};
      z = mfma16(F.a1[mt][0], b0, z);
      acc1[mt] = mfma16(F.a1[mt][1], b1, z);
    }
    // relu + pack: pk[mt][q] = fp16 pair for d = 16*mt + 4*g + {2q, 2q+1}
    u32 pk[7][2];
#pragma unroll
    for (int mt = 0; mt < 7; ++mt) {
      pk[mt][0] = pk2(fmaxf(acc1[mt][0], 0.f), fmaxf(acc1[mt][1], 0.f));
      pk[mt][1] = pk2(fmaxf(acc1[mt][2], 0.f), fmaxf(acc1[mt][3], 0.f));
    }
    // GEMM2: B2 word p of kt holds d = 32*kt + 8*g + {2p,2p+1}, gathered cross-lane
    f32x4 acc2[3];
#pragma unroll
    for (int m = 0; m < 3; ++m) acc2[m] = (f32x4){0.f, 0.f, 0.f, 0.f};
    const int srcBase = i15 + 32 * (g & 1);
    const bool sLow = (g < 2);
#pragma unroll
    for (int kt = 0; kt < 4; ++kt) {
      u32 wv[4];
#pragma unroll
      for (int p = 0; p < 4; ++p) {
        const int src = srcBase + 16 * (p >> 1);
        u32 vA = (u32)__shfl((int)pk[2 * kt][p & 1], src);
        u32 vB = 0u;
        if (kt < 3) vB = (u32)__shfl((int)pk[2 * kt + 1][p & 1], src);  // kt==3: d>=112 -> 0
        wv[p] = sLow ? vA : vB;
      }
      uint4 w4; w4.x = wv[0]; w4.y = wv[1]; w4.z = wv[2]; w4.w = wv[3];
      f16x8 b2 = __builtin_bit_cast(f16x8, w4);
#pragma unroll
      for (int m = 0; m < 3; ++m) acc2[m] = mfma16(F.a2[m][kt], b2, acc2[m]);
    }
    // write out: row = outrow + i15, cols c = 16*m + 4*g + {0..3}
    char* ob = smem + (outrow + i15) * ROWB + g * 8;
#pragma unroll
    for (int m = 0; m < 3; ++m) {
      uint2 w2;
      w2.x = pk2(acc2[m][0], acc2[m][1]);
      w2.y = pk2(acc2[m][2], acc2[m][3]);
      *(uint2*)(ob + m * 32) = w2;
    }
  }
}

// ---------------- sconv: out[o,c] = lfac(c) * sum_i w[o,i,l(c)] * in[i,c]
template <int O, int I, int SPL, int NSEG, int NIP, bool TW, int SEG>
__device__ __forceinline__ void sconv_acc_f(const float* __restrict__ wsrc, int o, int ip,
                                            bool act, const char* smem, int inArow, int inBrow,
                                            float* acc) {
  constexpr int GPS = 6 / NSEG;
  constexpr int NC = GPS * 8;
  constexpr int C0 = SEG * NC;
#pragma unroll
  for (int k = 0; k < NC; ++k) acc[k] = 0.f;
  if (!act) return;
  for (int i = ip; i < I; i += NIP) {
    const char* rb = smem + ((i < SPL) ? (inArow + i) : (inBrow + (i - SPL))) * ROWB;
    f16x8 xv[GPS];
#pragma unroll
    for (int g = 0; g < GPS; ++g) xv[g] = *(const f16x8*)(rb + C0 * 2 + g * 16);
    float w[5];
    if constexpr (TW) {
#pragma unroll
      for (int l = 0; l < 5; ++l) w[l] = wsrc[(i * 5 + l) * O + o];   // coalesced over o
    } else {
#pragma unroll
      for (int l = 0; l < 5; ++l) w[l] = wsrc[(o * I + i) * 5 + l];
    }
#pragma unroll
    for (int g = 0; g < GPS; ++g)
#pragma unroll
      for (int j = 0; j < 8; ++j)
        acc[g * 8 + j] += w[l_of(C0 + g * 8 + j)] * (float)xv[g][j];
  }
}

template <int NSEG, int SEG>
__device__ __forceinline__ void sconv_write_f(char* smem, int outrow, int o, const float* acc) {
  constexpr int GPS = 6 / NSEG;
  constexpr int C0 = SEG * GPS * 8;
  char* ob = smem + (outrow + o) * ROWB + C0 * 2;
#pragma unroll
  for (int g = 0; g < GPS; ++g) {
    u32 wv[4];
#pragma unroll
    for (int q = 0; q < 4; ++q) {
      const int k = g * 8 + 2 * q;
      const float a0 = acc[k] * lfac_of(l_of(C0 + k));
      const float a1 = acc[k + 1] * lfac_of(l_of(C0 + k + 1));
      wv[q] = pk2(a0, a1);
    }
    uint4 v4; v4.x = wv[0]; v4.y = wv[1]; v4.z = wv[2]; v4.w = wv[3];
    *(uint4*)(ob + g * 16) = v4;
  }
}

template <int O, int I, int SPL, int NSEG, int NIP, bool TW>
__device__ void sconv_layer(const float* __restrict__ wsrc, char* smem, int tid,
                            int inArow, int inBrow, int outrow) {
  constexpr int GPS = 6 / NSEG;
  constexpr int NC = GPS * 8;
  const int ip = (NIP == 1) ? 0 : (tid % NIP);
  const int seg = (tid / NIP) % NSEG;
  const int o = tid / (NIP * NSEG);
  const bool act = (o < O);
  float acc[NC];
  if (seg == 0)
    sconv_acc_f<O, I, SPL, NSEG, NIP, TW, 0>(wsrc, o, ip, act, smem, inArow, inBrow, acc);
  else if (seg == 1)
    sconv_acc_f<O, I, SPL, NSEG, NIP, TW, 1>(wsrc, o, ip, act, smem, inArow, inBrow, acc);
  else if constexpr (NSEG > 2) {
    sconv_acc_f<O, I, SPL, NSEG, NIP, TW, 2>(wsrc, o, ip, act, smem, inArow, inBrow, acc);
  }
  if constexpr (NIP >= 2) {
#pragma unroll
    for (int k = 0; k < NC; ++k) acc[k] += __shfl_xor(acc[k], 1);
  }
  if constexpr (NIP >= 4) {
#pragma unroll
    for (int k = 0; k < NC; ++k) acc[k] += __shfl_xor(acc[k], 2);
  }
  __syncthreads();   // all reads done before overwriting rows
  if (act && ip == 0) {
    if (seg == 0) sconv_write_f<NSEG, 0>(smem, outrow, o, acc);
    else if (seg == 1) sconv_write_f<NSEG, 1>(smem, outrow, o, acc);
    else if constexpr (NSEG > 2) { sconv_write_f<NSEG, 2>(smem, outrow, o, acc); }
  }
  __syncthreads();
}

// ---------------- prep kernel: bake fp16 A-fragments + transposed sconv weights into ws
__global__ void scnn_prep(const float* __restrict__ sft, const float* __restrict__ isft,
                          const float* __restrict__ w1, const float* __restrict__ w2,
                          const float* __restrict__ w3, const float* __restrict__ w4,
                          const float* __restrict__ w5, const float* __restrict__ w6,
                          const float* __restrict__ w7, const float* __restrict__ w8,
                          const float* __restrict__ w9, u32* __restrict__ wsfrag,
                          float* __restrict__ wT) {
  const int gid = blockIdx.x * 256 + threadIdx.x;
  if (gid < 3584) {  // A1: frag f = mt*2+kt, entry r = lane*4+word
    const int f = gid >> 8, r = gid & 255, ln = r >> 2, wd = r & 3;
    const int mt = f >> 1, kt = f & 1;
    const int d = 16 * mt + (ln & 15);
    const int c = 32 * kt + 8 * (ln >> 4) + 2 * wd;
    const float v0 = (d < 100 && c < 45) ? isft[d * 45 + c] : 0.f;
    const float v1 = (d < 100 && c + 1 < 45) ? isft[d * 45 + c + 1] : 0.f;
    wsfrag[gid] = pk2(v0, v1);
  } else if (gid < 6656) {  // A2: frag f = mt*4+kt
    const int e = gid - 3584;
    const int f = e >> 8, r = e & 255, ln = r >> 2, wd = r & 3;
    const int mt = f >> 2, kt = f & 3;
    const int c = 16 * mt + (ln & 15);
    const int d = 32 * kt + 8 * (ln >> 4) + 2 * wd;
    const float v0 = (c < 45 && d < 100) ? sft[c * 100 + d] : 0.f;
    const float v1 = (c < 45 && d + 1 < 100) ? sft[c * 100 + d + 1] : 0.f;
    wsfrag[gid] = pk2(v0, v1);
  } else if (gid < WS_FRAG_U32 + WT_FLOATS) {  // wT[layer][i][l][o] = w[o][i][l]
    const int e = gid - WS_FRAG_U32;
    const float* src; int I, O, off;
    if (e < 320)         { src = w1; I = 4;   O = 16;  off = 0; }
    else if (e < 2880)   { src = w2; I = 16;  O = 32;  off = 320; }
    else if (e < 13120)  { src = w3; I = 32;  O = 64;  off = 2880; }
    else if (e < 54080)  { src = w4; I = 64;  O = 128; off = 13120; }
    else if (e < 95040)  { src = w5; I = 128; O = 64;  off = 54080; }
    else if (e < 115520) { src = w6; I = 128; O = 32;  off = 95040; }
    else if (e < 120640) { src = w7; I = 64;  O = 16;  off = 115520; }
    else if (e < 123200) { src = w8; I = 32;  O = 16;  off = 120640; }
    else                 { src = w9; I = 16;  O = 1;   off = 123200; }
    const int e2 = e - off;
    const int i = e2 / (5 * O), l = (e2 / O) % 5, o = e2 % O;
    wT[e] = src[(o * I + i) * 5 + l];
  }
}

// ---------------- main fused kernel
template <bool TW>
__global__ __launch_bounds__(256, 2) void scnn_mfma(
    const float* __restrict__ x, const float* __restrict__ sft, const float* __restrict__ isft,
    const float* __restrict__ w1, const float* __restrict__ w2, const float* __restrict__ w3,
    const float* __restrict__ w4, const float* __restrict__ w5, const float* __restrict__ w6,
    const float* __restrict__ w7, const float* __restrict__ w8, const float* __restrict__ w9,
    const u32* __restrict__ wsfrag, const float* __restrict__ wT,
    float* __restrict__ out) {
  __shared__ __align__(16) char smem[NROWS * ROWB];
  const int tid = threadIdx.x, lane = tid & 63, wid = tid >> 6, b = blockIdx.x;

  Frags F;
  if constexpr (TW) {
    const uint4* p1 = (const uint4*)wsfrag;
#pragma unroll
    for (int f = 0; f < 14; ++f)
      F.a1[f / 2][f % 2] = __builtin_bit_cast(f16x8, p1[f * 64 + lane]);
    const uint4* p2 = p1 + 14 * 64;
#pragma unroll
    for (int f = 0; f < 12; ++f)
      F.a2[f / 4][f % 4] = __builtin_bit_cast(f16x8, p2[f * 64 + lane]);
  } else {
    const int i15 = lane & 15, g = lane >> 4;
#pragma unroll
    for (int mt = 0; mt < 7; ++mt)
#pragma unroll
      for (int kt = 0; kt < 2; ++kt) {
        const int d = 16 * mt + i15;
        f16x8 v;
#pragma unroll
        for (int j = 0; j < 8; ++j) {
          const int c = 32 * kt + 8 * g + j;
          v[j] = (half_t)((d < 100 && c < 45) ? isft[d * 45 + c] : 0.f);
        }
        F.a1[mt][kt] = v;
      }
#pragma unroll
    for (int mt = 0; mt < 3; ++mt)
#pragma unroll
      for (int kt = 0; kt < 4; ++kt) {
        const int c = 16 * mt + i15;
        f16x8 v;
#pragma unroll
        for (int j = 0; j < 8; ++j) {
          const int d = 32 * kt + 8 * g + j;
          v[j] = (half_t)((c < 45 && d < 100) ? sft[c * 100 + d] : 0.f);
        }
        F.a2[mt][kt] = v;
      }
  }

  // zero the pad region (bytes 96..144) of every row
  for (int r = tid; r < NROWS; r += 256) {
    u32* p = (u32*)(smem + r * ROWB + 96);
#pragma unroll
    for (int k = 0; k < 12; ++k) p[k] = 0u;
  }
  // stage x [4,45] fp32 -> rows 0..3 fp16 (cols 45..47 zeroed)
  if (tid < 192) {
    const int r = tid / 48, c = tid % 48;
    const float v = (c < 45) ? x[b * 180 + r * 45 + c] : 0.f;
    *(half_t*)(smem + r * ROWB + 2 * c) = (half_t)v;
  }
  __syncthreads();

  sconv_layer<16, 4, 4, 3, 4, TW>(TW ? wT + 0 : w1, smem, tid, 0, 0, 0);
  nonlin_tiles(F, smem, lane, wid, 1, 1, 0, 0, E1R, E1R);            // e1
  __syncthreads();
  sconv_layer<32, 16, 16, 2, 4, TW>(TW ? wT + 320 : w2, smem, tid, E1R, E1R, 0);
  nonlin_tiles(F, smem, lane, wid, 2, 2, 0, 0, E2R, E2R);            // e2
  __syncthreads();
  sconv_layer<64, 32, 32, 2, 2, TW>(TW ? wT + 2880 : w3, smem, tid, E2R, E2R, 0);
  nonlin_tiles(F, smem, lane, wid, 4, 4, 0, 0, E3R, E3R);            // e3
  __syncthreads();
  sconv_layer<128, 64, 64, 2, 1, TW>(TW ? wT + 13120 : w4, smem, tid, E3R, E3R, 0);
  nonlin_tiles(F, smem, lane, wid, 8, 8, 0, 0, 0, 0);                // e4 in place
  __syncthreads();
  sconv_layer<64, 128, 128, 2, 2, TW>(TW ? wT + 54080 : w5, smem, tid, 0, 0, 0);  // F -> rows 0..63
  nonlin_tiles(F, smem, lane, wid, 8, 4, 0, E3R, 0, E3R);            // d1 = nonlin([F;e3]) in place
  __syncthreads();
  sconv_layer<32, 128, 64, 2, 4, TW>(TW ? wT + 95040 : w6, smem, tid, 0, E3R, 0); // G -> rows 0..31
  nonlin_tiles(F, smem, lane, wid, 4, 2, 0, E2R, 0, E2R);            // d2 = nonlin([G;e2]) in place
  __syncthreads();
  sconv_layer<16, 64, 32, 3, 4, TW>(TW ? wT + 115520 : w7, smem, tid, 0, E2R, 0); // H -> rows 0..15
  nonlin_tiles(F, smem, lane, wid, 2, 1, 0, E1R, 0, E1R);            // d3 = nonlin([H;e1]) in place
  __syncthreads();
  sconv_layer<16, 32, 16, 3, 4, TW>(TW ? wT + 120640 : w8, smem, tid, 0, E1R, 0); // t8 -> rows 0..15
  nonlin_tiles(F, smem, lane, wid, 1, 1, 0, 0, 0, 0);                // d4 in place
  __syncthreads();

  // final sconv: O=1, I=16 -> out[b,c] fp32
  if (tid < 45) {
    const int c = tid, l = l_of(c);
    float acc = 0.f;
#pragma unroll
    for (int i = 0; i < 16; ++i)
      acc += w9[i * 5 + l] * (float)(*(const half_t*)(smem + i * ROWB + 2 * c));
    out[b * 45 + c] = acc * lfac_of(l);
  }
}

extern "C" void kernel_launch(void* const* d_in, const int* in_sizes, int n_in,
                              void* d_out, int out_size, void* d_ws, size_t ws_size,
                              hipStream_t stream) {
  (void)n_in; (void)out_size;
  const float* x    = (const float*)d_in[0];
  const float* sft  = (const float*)d_in[1];
  const float* isft = (const float*)d_in[2];
  const float* w1 = (const float*)d_in[3];
  const float* w2 = (const float*)d_in[4];
  const float* w3 = (const float*)d_in[5];
  const float* w4 = (const float*)d_in[6];
  const float* w5 = (const float*)d_in[7];
  const float* w6 = (const float*)d_in[8];
  const float* w7 = (const float*)d_in[9];
  const float* w8 = (const float*)d_in[10];
  const float* w9 = (const float*)d_in[11];
  float* out = (float*)d_out;

  const int batch = in_sizes[0] / 180;  // 16384

  if (ws_size >= (size_t)WS_NEEDED) {
    u32* wsfrag = (u32*)d_ws;
    float* wT = (float*)d_ws + WS_FRAG_U32;
    const int prepN = WS_FRAG_U32 + WT_FLOATS;
    hipLaunchKernelGGL(scnn_prep, dim3((prepN + 255) / 256), dim3(256), 0, stream,
                       sft, isft, w1, w2, w3, w4, w5, w6, w7, w8, w9, wsfrag, wT);
    hipLaunchKernelGGL((scnn_mfma<true>), dim3(batch), dim3(256), 0, stream,
                       x, sft, isft, w1, w2, w3, w4, w5, w6, w7, w8, w9, wsfrag, wT, out);
  } else {
    hipLaunchKernelGGL((scnn_mfma<false>), dim3(batch), dim3(256), 0, stream,
                       x, sft, isft, w1, w2, w3, w4, w5, w6, w7, w8, w9,
                       (const u32*)nullptr, (const float*)nullptr, out);
  }
}

// Round 6
// 2553.412 us; speedup vs baseline: 5.7797x; 1.1175x over previous
//
#include <hip/hip_runtime.h>
#include <math.h>

// SCNN fused, round 6: round-5 pair-interleaved layout with three fixes:
//  (1) mergepair via portable shift/mask (no __builtin_amdgcn_perm semantics risk)
//  (2) PRB 192 -> 272 (64 c's/row, c>=48 zeroed once) -> GEMM1 reads stay in-row
//      against zeros (round-4 invariant restored) and rows are bank-conflict-free
//  (3) weights packed RNE
// nonlin via fp16 MFMA (16x16x32), sconv via v_dot2_f32_f16 pairs. 4 blocks/CU.

typedef _Float16 half_t;
typedef _Float16 f16x8 __attribute__((ext_vector_type(8)));
typedef __fp16 h2 __attribute__((ext_vector_type(2)));
typedef float f32x4 __attribute__((ext_vector_type(4)));
typedef unsigned int u32;

#define PRB 272    // bytes per pair-row: 64 c * 4B + 16 slack; 272/4 % 32 == 4 -> conflict-free
#define NPAIRS 120 // 240 logical rows
#define E1R 128
#define E2R 144
#define E3R 176

// ws layout (u32): [0,3584) A1 frags, [3584,6656) A2 frags, [6656, +61640) paired weights
#define WS_FRAG_U32 6656
#define WP_U32 61640
#define WS_NEEDED ((WS_FRAG_U32 + WP_U32) * 4)

__device__ __host__ __forceinline__ constexpr int l_of(int c) {
  return (c >= 1) + (c >= 6) + (c >= 15) + (c >= 28);
}
__device__ __forceinline__ float lfac_of(int l) {
  return sqrtf(3.14159265358979323846f / (float)(4 * l + 1));
}
// RTZ pack (hardware v_cvt_pkrtz) — hot path, round-4-verified numerics
__device__ __forceinline__ u32 pk2(float a, float b) {
  auto v = __builtin_amdgcn_cvt_pkrtz(a, b);
  return __builtin_bit_cast(u32, v);
}
// RNE pack — for weight/frag baking (cold path, better rounding)
__device__ __forceinline__ u32 pk2rne(float a, float b) {
  unsigned short lo = __builtin_bit_cast(unsigned short, (half_t)a);
  unsigned short hi = __builtin_bit_cast(unsigned short, (half_t)b);
  return (u32)lo | ((u32)hi << 16);
}
// D = S0.x*S1.x + S0.y*S1.y + S2  (fp16 mul, fp32 accumulate)
__device__ __forceinline__ float dot2(u32 xp, u32 wp, float acc) {
#if __has_builtin(__builtin_amdgcn_fdot2)
  return __builtin_amdgcn_fdot2(__builtin_bit_cast(h2, xp), __builtin_bit_cast(h2, wp), acc, false);
#else
  h2 xv = __builtin_bit_cast(h2, xp), wv = __builtin_bit_cast(h2, wp);
  return acc + (float)xv[0] * (float)wv[0] + (float)xv[1] * (float)wv[1];
#endif
}
// a = dword at col c (lo16=row_even[c], hi16=row_odd[c]), b = same at c+1.
// Returns [row_par[c], row_par[c+1]] as two fp16 in one dword. Portable ops.
__device__ __forceinline__ u32 mergepair(u32 a, u32 b, int par) {
  return par ? ((a >> 16) | (b & 0xffff0000u))
             : ((a & 0x0000ffffu) | (b << 16));
}
__device__ __forceinline__ f32x4 mfma16(f16x8 a, f16x8 b, f32x4 c) {
  return __builtin_amdgcn_mfma_f32_16x16x32_f16(a, b, c, 0, 0, 0);
}

struct Frags {
  f16x8 a1[7][2];  // isft: d = 16*mt + (l&15), k=c = 32*kt + 8*(l>>4) + j (0 pad)
  f16x8 a2[3][4];  // sft:  c = 16*mt + (l&15), k=d = 32*kt + 8*(l>>4) + j (0 pad)
};

// read 8 consecutive-c fp16 of row parity par from a pair-row base (c0 8-aligned)
__device__ __forceinline__ f16x8 ldpair8(const char* base, int par) {
  const uint4 q0 = *(const uint4*)(base);
  const uint4 q1 = *(const uint4*)(base + 16);
  uint4 r;
  r.x = mergepair(q0.x, q0.y, par);
  r.y = mergepair(q0.z, q0.w, par);
  r.z = mergepair(q1.x, q1.y, par);
  r.w = mergepair(q1.z, q1.w, par);
  return __builtin_bit_cast(f16x8, r);
}

// ---------------- nonlin: out[r,c] = sum_d sft[c,d] * relu(sum_c' isft[d,c'] in[r,c'])
__device__ void nonlin_tiles(const Frags& F, char* smem, int lane, int wid,
                             int T, int TA, int inArow, int inBrow,
                             int outArow, int outBrow) {
  const int i15 = lane & 15, g = lane >> 4;
  for (int t = wid; t < T; t += 4) {
    const int inrow = (t < TA) ? (inArow + t * 16) : (inBrow + (t - TA) * 16);
    const int outrow = (t < TA) ? (outArow + t * 16) : (outBrow + (t - TA) * 16);
    const int R = inrow + i15, par = R & 1;
    const char* ib = smem + (R >> 1) * PRB + g * 32;
    f16x8 b0 = ldpair8(ib, par);        // c = 8g + j
    f16x8 b1 = ldpair8(ib + 128, par);  // c = 32 + 8g + j  (c>=48 zeroed pad)
    f32x4 acc1[7];
#pragma unroll
    for (int mt = 0; mt < 7; ++mt) {
      f32x4 z = {0.f, 0.f, 0.f, 0.f};
      z = mfma16(F.a1[mt][0], b0, z);
      acc1[mt] = mfma16(F.a1[mt][1], b1, z);
    }
    // relu + pack: pk[mt][q] = fp16 pair for d = 16*mt + 4*g + {2q, 2q+1}
    u32 pk[7][2];
#pragma unroll
    for (int mt = 0; mt < 7; ++mt) {
      pk[mt][0] = pk2(fmaxf(acc1[mt][0], 0.f), fmaxf(acc1[mt][1], 0.f));
      pk[mt][1] = pk2(fmaxf(acc1[mt][2], 0.f), fmaxf(acc1[mt][3], 0.f));
    }
    // GEMM2: B2 word p of kt holds d = 32*kt + 8*g + {2p,2p+1}, gathered cross-lane
    f32x4 acc2[3];
#pragma unroll
    for (int m = 0; m < 3; ++m) acc2[m] = (f32x4){0.f, 0.f, 0.f, 0.f};
    const int srcBase = i15 + 32 * (g & 1);
    const bool sLow = (g < 2);
#pragma unroll
    for (int kt = 0; kt < 4; ++kt) {
      u32 wv[4];
#pragma unroll
      for (int p = 0; p < 4; ++p) {
        const int src = srcBase + 16 * (p >> 1);
        u32 vA = (u32)__shfl((int)pk[2 * kt][p & 1], src);
        u32 vB = 0u;
        if (kt < 3) vB = (u32)__shfl((int)pk[2 * kt + 1][p & 1], src);  // kt==3: d>=112 -> 0
        wv[p] = sLow ? vA : vB;
      }
      uint4 w4; w4.x = wv[0]; w4.y = wv[1]; w4.z = wv[2]; w4.w = wv[3];
      f16x8 b2 = __builtin_bit_cast(f16x8, w4);
#pragma unroll
      for (int m = 0; m < 3; ++m) acc2[m] = mfma16(F.a2[m][kt], b2, acc2[m]);
    }
    // write: row Ro = outrow + i15, cols c = 16*m + 4*g + j (16-bit stores, paired layout)
    const int Ro = outrow + i15;
    char* ob = smem + (Ro >> 1) * PRB + (Ro & 1) * 2 + g * 16;
#pragma unroll
    for (int m = 0; m < 3; ++m)
#pragma unroll
      for (int j = 0; j < 4; ++j)
        *(half_t*)(ob + m * 64 + j * 4) = (half_t)acc2[m][j];
  }
}

// ---------------- sconv via v_dot2: out[o,c] = lfac(c) * sum_i w[o,i,l(c)] * in[i,c]
template <int O, int I, int SPL, int NSEG, int NIP, bool TW, int SEG>
__device__ __forceinline__ void sconv_acc_p(const void* __restrict__ wsrc, int o, int ip,
                                            bool act, const char* smem, int inArow, int inBrow,
                                            float* acc) {
  constexpr int NC = 48 / NSEG;
  constexpr int NU4 = NC / 4;
  constexpr int C0 = SEG * NC;
#pragma unroll
  for (int k = 0; k < NC; ++k) acc[k] = 0.f;
  if (!act) return;
  const u32* __restrict__ wp = (const u32*)wsrc;
  const float* __restrict__ wf = (const float*)wsrc;
#pragma unroll 2
  for (int p = ip; p < I / 2; p += NIP) {
    const int rA = 2 * p;
    const char* rb = smem +
        (((rA < SPL) ? ((inArow >> 1) + p) : ((inBrow >> 1) + p - SPL / 2)) * PRB) + C0 * 4;
    u32 wv[5];
    if constexpr (TW) {
#pragma unroll
      for (int l = 0; l < 5; ++l) wv[l] = wp[(p * 5 + l) * O + o];  // coalesced over o
    } else {
#pragma unroll
      for (int l = 0; l < 5; ++l)
        wv[l] = pk2rne(wf[(o * I + rA) * 5 + l], wf[(o * I + rA + 1) * 5 + l]);
    }
#pragma unroll
    for (int k = 0; k < NU4; ++k) {
      const uint4 q = *(const uint4*)(rb + k * 16);  // 4 c's, both rows of the pair
      const u32 qq[4] = {q.x, q.y, q.z, q.w};
#pragma unroll
      for (int j = 0; j < 4; ++j) {
        const int c = C0 + k * 4 + j;
        acc[k * 4 + j] = dot2(qq[j], wv[l_of(c)], acc[k * 4 + j]);
      }
    }
  }
}

template <int NSEG, int SEG>
__device__ __forceinline__ void sconv_write_p(char* smem, int outrow, int o, const float* acc) {
  constexpr int NC = 48 / NSEG;
  constexpr int C0 = SEG * NC;
  const int R = outrow + o;
  char* wb = smem + (R >> 1) * PRB + (R & 1) * 2 + C0 * 4;
#pragma unroll
  for (int k = 0; k < NC; ++k) {
    const int c = C0 + k;
    *(half_t*)(wb + k * 4) = (half_t)(acc[k] * lfac_of(l_of(c)));
  }
}

template <int O, int I, int SPL, int NSEG, int NIP, bool TW>
__device__ void sconv_layer(const void* __restrict__ wsrc, char* smem, int tid,
                            int inArow, int inBrow, int outrow) {
  constexpr int NC = 48 / NSEG;
  const int ip = (NIP == 1) ? 0 : (tid % NIP);
  const int seg = (tid / NIP) % NSEG;
  const int o = tid / (NIP * NSEG);
  const bool act = (o < O);
  float acc[NC];
  if (seg == 0)
    sconv_acc_p<O, I, SPL, NSEG, NIP, TW, 0>(wsrc, o, ip, act, smem, inArow, inBrow, acc);
  else if (seg == 1)
    sconv_acc_p<O, I, SPL, NSEG, NIP, TW, 1>(wsrc, o, ip, act, smem, inArow, inBrow, acc);
  else if constexpr (NSEG > 2) {
    sconv_acc_p<O, I, SPL, NSEG, NIP, TW, 2>(wsrc, o, ip, act, smem, inArow, inBrow, acc);
  }
  if constexpr (NIP >= 2) {
#pragma unroll
    for (int k = 0; k < NC; ++k) acc[k] += __shfl_xor(acc[k], 1);
  }
  if constexpr (NIP >= 4) {
#pragma unroll
    for (int k = 0; k < NC; ++k) acc[k] += __shfl_xor(acc[k], 2);
  }
  __syncthreads();  // all reads done before overwriting rows
  if (act && ip == 0) {
    if (seg == 0) sconv_write_p<NSEG, 0>(smem, outrow, o, acc);
    else if (seg == 1) sconv_write_p<NSEG, 1>(smem, outrow, o, acc);
    else if constexpr (NSEG > 2) { sconv_write_p<NSEG, 2>(smem, outrow, o, acc); }
  }
  __syncthreads();
}

// ---------------- prep: bake fp16 A-fragments + paired fp16 sconv weights into ws
__global__ void scnn_prep(const float* __restrict__ sft, const float* __restrict__ isft,
                          const float* __restrict__ w1, const float* __restrict__ w2,
                          const float* __restrict__ w3, const float* __restrict__ w4,
                          const float* __restrict__ w5, const float* __restrict__ w6,
                          const float* __restrict__ w7, const float* __restrict__ w8,
                          const float* __restrict__ w9, u32* __restrict__ wsbuf) {
  const int gid = blockIdx.x * 256 + threadIdx.x;
  if (gid < 3584) {  // A1 frags
    const int f = gid >> 8, r = gid & 255, ln = r >> 2, wd = r & 3;
    const int mt = f >> 1, kt = f & 1;
    const int d = 16 * mt + (ln & 15);
    const int c = 32 * kt + 8 * (ln >> 4) + 2 * wd;
    const float v0 = (d < 100 && c < 45) ? isft[d * 45 + c] : 0.f;
    const float v1 = (d < 100 && c + 1 < 45) ? isft[d * 45 + c + 1] : 0.f;
    wsbuf[gid] = pk2rne(v0, v1);
  } else if (gid < WS_FRAG_U32) {  // A2 frags
    const int e = gid - 3584;
    const int f = e >> 8, r = e & 255, ln = r >> 2, wd = r & 3;
    const int mt = f >> 2, kt = f & 3;
    const int c = 16 * mt + (ln & 15);
    const int d = 32 * kt + 8 * (ln >> 4) + 2 * wd;
    const float v0 = (c < 45 && d < 100) ? sft[c * 100 + d] : 0.f;
    const float v1 = (c < 45 && d + 1 < 100) ? sft[c * 100 + d + 1] : 0.f;
    wsbuf[gid] = pk2rne(v0, v1);
  } else if (gid < WS_FRAG_U32 + WP_U32) {  // paired weights: [p][l][o] u32
    const int e = gid - WS_FRAG_U32;
    const float* src; int I, O, off;
    if (e < 160)        { src = w1; I = 4;   O = 16;  off = 0; }
    else if (e < 1440)  { src = w2; I = 16;  O = 32;  off = 160; }
    else if (e < 6560)  { src = w3; I = 32;  O = 64;  off = 1440; }
    else if (e < 27040) { src = w4; I = 64;  O = 128; off = 6560; }
    else if (e < 47520) { src = w5; I = 128; O = 64;  off = 27040; }
    else if (e < 57760) { src = w6; I = 128; O = 32;  off = 47520; }
    else if (e < 60320) { src = w7; I = 64;  O = 16;  off = 57760; }
    else if (e < 61600) { src = w8; I = 32;  O = 16;  off = 60320; }
    else                { src = w9; I = 16;  O = 1;   off = 61600; }
    const int e2 = e - off;
    const int p = e2 / (5 * O), l = (e2 / O) % 5, o = e2 % O;
    wsbuf[e + WS_FRAG_U32] = pk2rne(src[(o * I + 2 * p) * 5 + l], src[(o * I + 2 * p + 1) * 5 + l]);
  }
}

// ---------------- main fused kernel
template <bool TW>
__global__ __launch_bounds__(256, 4) void scnn_mfma(
    const float* __restrict__ x, const float* __restrict__ sft, const float* __restrict__ isft,
    const float* __restrict__ w1, const float* __restrict__ w2, const float* __restrict__ w3,
    const float* __restrict__ w4, const float* __restrict__ w5, const float* __restrict__ w6,
    const float* __restrict__ w7, const float* __restrict__ w8, const float* __restrict__ w9,
    const u32* __restrict__ wsbuf, float* __restrict__ out) {
  __shared__ __align__(16) char smem[NPAIRS * PRB];
  const int tid = threadIdx.x, lane = tid & 63, wid = tid >> 6, b = blockIdx.x;
  const u32* wp = TW ? (wsbuf + WS_FRAG_U32) : nullptr;

  Frags F;
  if constexpr (TW) {
    const uint4* p1 = (const uint4*)wsbuf;
#pragma unroll
    for (int f = 0; f < 14; ++f)
      F.a1[f / 2][f % 2] = __builtin_bit_cast(f16x8, p1[f * 64 + lane]);
    const uint4* p2 = p1 + 14 * 64;
#pragma unroll
    for (int f = 0; f < 12; ++f)
      F.a2[f / 4][f % 4] = __builtin_bit_cast(f16x8, p2[f * 64 + lane]);
  } else {
    const int i15 = lane & 15, g = lane >> 4;
#pragma unroll
    for (int mt = 0; mt < 7; ++mt)
#pragma unroll
      for (int kt = 0; kt < 2; ++kt) {
        const int d = 16 * mt + i15;
        f16x8 v;
#pragma unroll
        for (int j = 0; j < 8; ++j) {
          const int c = 32 * kt + 8 * g + j;
          v[j] = (half_t)((d < 100 && c < 45) ? isft[d * 45 + c] : 0.f);
        }
        F.a1[mt][kt] = v;
      }
#pragma unroll
    for (int mt = 0; mt < 3; ++mt)
#pragma unroll
      for (int kt = 0; kt < 4; ++kt) {
        const int c = 16 * mt + i15;
        f16x8 v;
#pragma unroll
        for (int j = 0; j < 8; ++j) {
          const int d = 32 * kt + 8 * g + j;
          v[j] = (half_t)((c < 45 && d < 100) ? sft[c * 100 + d] : 0.f);
        }
        F.a2[mt][kt] = v;
      }
  }

  // zero pad region of every pair row: bytes 192..272 (c = 48..63 + slack).
  // Writes below never touch c >= 48, so this stays zero for the whole kernel.
  for (int idx = tid; idx < NPAIRS * 20; idx += 256) {
    const int pr = idx / 20, w = idx % 20;
    *(u32*)(smem + pr * PRB + 192 + w * 4) = 0u;
  }
  // stage x [4,45] -> rows 0..3 (paired layout), pads c=45..47 zeroed
  if (tid < 192) {
    const int r = tid / 48, c = tid % 48;
    const float v = (c < 45) ? x[b * 180 + r * 45 + c] : 0.f;
    *(half_t*)(smem + (r >> 1) * PRB + c * 4 + (r & 1) * 2) = (half_t)v;
  }
  __syncthreads();

  sconv_layer<16, 4, 4, 3, 4, TW>(TW ? (const void*)(wp + 0) : (const void*)w1, smem, tid, 0, 0, 0);
  nonlin_tiles(F, smem, lane, wid, 1, 1, 0, 0, E1R, E1R);            // e1
  __syncthreads();
  sconv_layer<32, 16, 16, 2, 4, TW>(TW ? (const void*)(wp + 160) : (const void*)w2, smem, tid, E1R, E1R, 0);
  nonlin_tiles(F, smem, lane, wid, 2, 2, 0, 0, E2R, E2R);            // e2
  __syncthreads();
  sconv_layer<64, 32, 32, 2, 2, TW>(TW ? (const void*)(wp + 1440) : (const void*)w3, smem, tid, E2R, E2R, 0);
  nonlin_tiles(F, smem, lane, wid, 4, 4, 0, 0, E3R, E3R);            // e3
  __syncthreads();
  sconv_layer<128, 64, 64, 2, 1, TW>(TW ? (const void*)(wp + 6560) : (const void*)w4, smem, tid, E3R, E3R, 0);
  nonlin_tiles(F, smem, lane, wid, 8, 8, 0, 0, 0, 0);                // e4 in place (rows 0..127)
  __syncthreads();
  sconv_layer<64, 128, 128, 2, 2, TW>(TW ? (const void*)(wp + 27040) : (const void*)w5, smem, tid, 0, 0, 0);  // F -> rows 0..63
  nonlin_tiles(F, smem, lane, wid, 8, 4, 0, E3R, 0, E3R);            // d1 = nonlin([F;e3]) in place
  __syncthreads();
  sconv_layer<32, 128, 64, 2, 4, TW>(TW ? (const void*)(wp + 47520) : (const void*)w6, smem, tid, 0, E3R, 0); // G -> rows 0..31
  nonlin_tiles(F, smem, lane, wid, 4, 2, 0, E2R, 0, E2R);            // d2 = nonlin([G;e2]) in place
  __syncthreads();
  sconv_layer<16, 64, 32, 3, 4, TW>(TW ? (const void*)(wp + 57760) : (const void*)w7, smem, tid, 0, E2R, 0);  // H -> rows 0..15
  nonlin_tiles(F, smem, lane, wid, 2, 1, 0, E1R, 0, E1R);            // d3 = nonlin([H;e1]) in place
  __syncthreads();
  sconv_layer<16, 32, 16, 3, 4, TW>(TW ? (const void*)(wp + 60320) : (const void*)w8, smem, tid, 0, E1R, 0);  // t8 -> rows 0..15
  nonlin_tiles(F, smem, lane, wid, 1, 1, 0, 0, 0, 0);                // d4 in place (rows 0..15)
  __syncthreads();

  // final sconv: O=1, I=16 (d4 rows 0..15) -> out[b,c] fp32
  if (tid < 45) {
    const int c = tid, l = l_of(c);
    float acc = 0.f;
#pragma unroll
    for (int i = 0; i < 16; ++i)
      acc += w9[i * 5 + l] *
             (float)(*(const half_t*)(smem + (i >> 1) * PRB + c * 4 + (i & 1) * 2));
    out[b * 45 + c] = acc * lfac_of(l);
  }
}

extern "C" void kernel_launch(void* const* d_in, const int* in_sizes, int n_in,
                              void* d_out, int out_size, void* d_ws, size_t ws_size,
                              hipStream_t stream) {
  (void)n_in; (void)out_size;
  const float* x    = (const float*)d_in[0];
  const float* sft  = (const float*)d_in[1];
  const float* isft = (const float*)d_in[2];
  const float* w1 = (const float*)d_in[3];
  const float* w2 = (const float*)d_in[4];
  const float* w3 = (const float*)d_in[5];
  const float* w4 = (const float*)d_in[6];
  const float* w5 = (const float*)d_in[7];
  const float* w6 = (const float*)d_in[8];
  const float* w7 = (const float*)d_in[9];
  const float* w8 = (const float*)d_in[10];
  const float* w9 = (const float*)d_in[11];
  float* out = (float*)d_out;

  const int batch = in_sizes[0] / 180;  // 16384

  if (ws_size >= (size_t)WS_NEEDED) {
    u32* wsbuf = (u32*)d_ws;
    const int prepN = WS_FRAG_U32 + WP_U32;
    hipLaunchKernelGGL(scnn_prep, dim3((prepN + 255) / 256), dim3(256), 0, stream,
                       sft, isft, w1, w2, w3, w4, w5, w6, w7, w8, w9, wsbuf);
    hipLaunchKernelGGL((scnn_mfma<true>), dim3(batch), dim3(256), 0, stream,
                       x, sft, isft, w1, w2, w3, w4, w5, w6, w7, w8, w9, wsbuf, out);
  } else {
    hipLaunchKernelGGL((scnn_mfma<false>), dim3(batch), dim3(256), 0, stream,
                       x, sft, isft, w1, w2, w3, w4, w5, w6, w7, w8, w9,
                       (const u32*)nullptr, out);
  }
}

// Round 7
// 1790.292 us; speedup vs baseline: 8.2433x; 1.4263x over previous
//
#include <hip/hip_runtime.h>
#include <math.h>

// SCNN fused, round 7: round-6 kernel with __launch_bounds__(256,2).
// Round 6's (256,4) capped VGPRs at 64 -> the 104-VGPR MFMA fragment table
// spilled to scratch (FETCH 9MB->2.7GB). (256,2) keeps F register-resident.
// nonlin via fp16 MFMA (16x16x32), sconv via v_dot2_f32_f16 pairs.

typedef _Float16 half_t;
typedef _Float16 f16x8 __attribute__((ext_vector_type(8)));
typedef __fp16 h2 __attribute__((ext_vector_type(2)));
typedef float f32x4 __attribute__((ext_vector_type(4)));
typedef unsigned int u32;

#define PRB 272    // bytes per pair-row: 64 c * 4B + 16 slack; 272/4 % 32 == 4 -> conflict-free
#define NPAIRS 120 // 240 logical rows
#define E1R 128
#define E2R 144
#define E3R 176

// ws layout (u32): [0,3584) A1 frags, [3584,6656) A2 frags, [6656, +61640) paired weights
#define WS_FRAG_U32 6656
#define WP_U32 61640
#define WS_NEEDED ((WS_FRAG_U32 + WP_U32) * 4)

__device__ __host__ __forceinline__ constexpr int l_of(int c) {
  return (c >= 1) + (c >= 6) + (c >= 15) + (c >= 28);
}
__device__ __forceinline__ float lfac_of(int l) {
  return sqrtf(3.14159265358979323846f / (float)(4 * l + 1));
}
// RTZ pack (hardware v_cvt_pkrtz) — hot path, round-4-verified numerics
__device__ __forceinline__ u32 pk2(float a, float b) {
  auto v = __builtin_amdgcn_cvt_pkrtz(a, b);
  return __builtin_bit_cast(u32, v);
}
// RNE pack — for weight/frag baking (cold path, better rounding)
__device__ __forceinline__ u32 pk2rne(float a, float b) {
  unsigned short lo = __builtin_bit_cast(unsigned short, (half_t)a);
  unsigned short hi = __builtin_bit_cast(unsigned short, (half_t)b);
  return (u32)lo | ((u32)hi << 16);
}
// D = S0.x*S1.x + S0.y*S1.y + S2  (fp16 mul, fp32 accumulate)
__device__ __forceinline__ float dot2(u32 xp, u32 wp, float acc) {
#if __has_builtin(__builtin_amdgcn_fdot2)
  return __builtin_amdgcn_fdot2(__builtin_bit_cast(h2, xp), __builtin_bit_cast(h2, wp), acc, false);
#else
  h2 xv = __builtin_bit_cast(h2, xp), wv = __builtin_bit_cast(h2, wp);
  return acc + (float)xv[0] * (float)wv[0] + (float)xv[1] * (float)wv[1];
#endif
}
// a = dword at col c (lo16=row_even[c], hi16=row_odd[c]), b = same at c+1.
// Returns [row_par[c], row_par[c+1]] as two fp16 in one dword. Portable ops.
__device__ __forceinline__ u32 mergepair(u32 a, u32 b, int par) {
  return par ? ((a >> 16) | (b & 0xffff0000u))
             : ((a & 0x0000ffffu) | (b << 16));
}
__device__ __forceinline__ f32x4 mfma16(f16x8 a, f16x8 b, f32x4 c) {
  return __builtin_amdgcn_mfma_f32_16x16x32_f16(a, b, c, 0, 0, 0);
}

struct Frags {
  f16x8 a1[7][2];  // isft: d = 16*mt + (l&15), k=c = 32*kt + 8*(l>>4) + j (0 pad)
  f16x8 a2[3][4];  // sft:  c = 16*mt + (l&15), k=d = 32*kt + 8*(l>>4) + j (0 pad)
};

// read 8 consecutive-c fp16 of row parity par from a pair-row base (c0 8-aligned)
__device__ __forceinline__ f16x8 ldpair8(const char* base, int par) {
  const uint4 q0 = *(const uint4*)(base);
  const uint4 q1 = *(const uint4*)(base + 16);
  uint4 r;
  r.x = mergepair(q0.x, q0.y, par);
  r.y = mergepair(q0.z, q0.w, par);
  r.z = mergepair(q1.x, q1.y, par);
  r.w = mergepair(q1.z, q1.w, par);
  return __builtin_bit_cast(f16x8, r);
}

// ---------------- nonlin: out[r,c] = sum_d sft[c,d] * relu(sum_c' isft[d,c'] in[r,c'])
__device__ void nonlin_tiles(const Frags& F, char* smem, int lane, int wid,
                             int T, int TA, int inArow, int inBrow,
                             int outArow, int outBrow) {
  const int i15 = lane & 15, g = lane >> 4;
  for (int t = wid; t < T; t += 4) {
    const int inrow = (t < TA) ? (inArow + t * 16) : (inBrow + (t - TA) * 16);
    const int outrow = (t < TA) ? (outArow + t * 16) : (outBrow + (t - TA) * 16);
    const int R = inrow + i15, par = R & 1;
    const char* ib = smem + (R >> 1) * PRB + g * 32;
    f16x8 b0 = ldpair8(ib, par);        // c = 8g + j
    f16x8 b1 = ldpair8(ib + 128, par);  // c = 32 + 8g + j  (c>=48 zeroed pad)
    f32x4 acc1[7];
#pragma unroll
    for (int mt = 0; mt < 7; ++mt) {
      f32x4 z = {0.f, 0.f, 0.f, 0.f};
      z = mfma16(F.a1[mt][0], b0, z);
      acc1[mt] = mfma16(F.a1[mt][1], b1, z);
    }
    // relu + pack: pk[mt][q] = fp16 pair for d = 16*mt + 4*g + {2q, 2q+1}
    u32 pk[7][2];
#pragma unroll
    for (int mt = 0; mt < 7; ++mt) {
      pk[mt][0] = pk2(fmaxf(acc1[mt][0], 0.f), fmaxf(acc1[mt][1], 0.f));
      pk[mt][1] = pk2(fmaxf(acc1[mt][2], 0.f), fmaxf(acc1[mt][3], 0.f));
    }
    // GEMM2: B2 word p of kt holds d = 32*kt + 8*g + {2p,2p+1}, gathered cross-lane
    f32x4 acc2[3];
#pragma unroll
    for (int m = 0; m < 3; ++m) acc2[m] = (f32x4){0.f, 0.f, 0.f, 0.f};
    const int srcBase = i15 + 32 * (g & 1);
    const bool sLow = (g < 2);
#pragma unroll
    for (int kt = 0; kt < 4; ++kt) {
      u32 wv[4];
#pragma unroll
      for (int p = 0; p < 4; ++p) {
        const int src = srcBase + 16 * (p >> 1);
        u32 vA = (u32)__shfl((int)pk[2 * kt][p & 1], src);
        u32 vB = 0u;
        if (kt < 3) vB = (u32)__shfl((int)pk[2 * kt + 1][p & 1], src);  // kt==3: d>=112 -> 0
        wv[p] = sLow ? vA : vB;
      }
      uint4 w4; w4.x = wv[0]; w4.y = wv[1]; w4.z = wv[2]; w4.w = wv[3];
      f16x8 b2 = __builtin_bit_cast(f16x8, w4);
#pragma unroll
      for (int m = 0; m < 3; ++m) acc2[m] = mfma16(F.a2[m][kt], b2, acc2[m]);
    }
    // write: row Ro = outrow + i15, cols c = 16*m + 4*g + j (16-bit stores, paired layout)
    const int Ro = outrow + i15;
    char* ob = smem + (Ro >> 1) * PRB + (Ro & 1) * 2 + g * 16;
#pragma unroll
    for (int m = 0; m < 3; ++m)
#pragma unroll
      for (int j = 0; j < 4; ++j)
        *(half_t*)(ob + m * 64 + j * 4) = (half_t)acc2[m][j];
  }
}

// ---------------- sconv via v_dot2: out[o,c] = lfac(c) * sum_i w[o,i,l(c)] * in[i,c]
template <int O, int I, int SPL, int NSEG, int NIP, bool TW, int SEG>
__device__ __forceinline__ void sconv_acc_p(const void* __restrict__ wsrc, int o, int ip,
                                            bool act, const char* smem, int inArow, int inBrow,
                                            float* acc) {
  constexpr int NC = 48 / NSEG;
  constexpr int NU4 = NC / 4;
  constexpr int C0 = SEG * NC;
#pragma unroll
  for (int k = 0; k < NC; ++k) acc[k] = 0.f;
  if (!act) return;
  const u32* __restrict__ wp = (const u32*)wsrc;
  const float* __restrict__ wf = (const float*)wsrc;
#pragma unroll 2
  for (int p = ip; p < I / 2; p += NIP) {
    const int rA = 2 * p;
    const char* rb = smem +
        (((rA < SPL) ? ((inArow >> 1) + p) : ((inBrow >> 1) + p - SPL / 2)) * PRB) + C0 * 4;
    u32 wv[5];
    if constexpr (TW) {
#pragma unroll
      for (int l = 0; l < 5; ++l) wv[l] = wp[(p * 5 + l) * O + o];  // coalesced over o
    } else {
#pragma unroll
      for (int l = 0; l < 5; ++l)
        wv[l] = pk2rne(wf[(o * I + rA) * 5 + l], wf[(o * I + rA + 1) * 5 + l]);
    }
#pragma unroll
    for (int k = 0; k < NU4; ++k) {
      const uint4 q = *(const uint4*)(rb + k * 16);  // 4 c's, both rows of the pair
      const u32 qq[4] = {q.x, q.y, q.z, q.w};
#pragma unroll
      for (int j = 0; j < 4; ++j) {
        const int c = C0 + k * 4 + j;
        acc[k * 4 + j] = dot2(qq[j], wv[l_of(c)], acc[k * 4 + j]);
      }
    }
  }
}

template <int NSEG, int SEG>
__device__ __forceinline__ void sconv_write_p(char* smem, int outrow, int o, const float* acc) {
  constexpr int NC = 48 / NSEG;
  constexpr int C0 = SEG * NC;
  const int R = outrow + o;
  char* wb = smem + (R >> 1) * PRB + (R & 1) * 2 + C0 * 4;
#pragma unroll
  for (int k = 0; k < NC; ++k) {
    const int c = C0 + k;
    *(half_t*)(wb + k * 4) = (half_t)(acc[k] * lfac_of(l_of(c)));
  }
}

template <int O, int I, int SPL, int NSEG, int NIP, bool TW>
__device__ void sconv_layer(const void* __restrict__ wsrc, char* smem, int tid,
                            int inArow, int inBrow, int outrow) {
  constexpr int NC = 48 / NSEG;
  const int ip = (NIP == 1) ? 0 : (tid % NIP);
  const int seg = (tid / NIP) % NSEG;
  const int o = tid / (NIP * NSEG);
  const bool act = (o < O);
  float acc[NC];
  if (seg == 0)
    sconv_acc_p<O, I, SPL, NSEG, NIP, TW, 0>(wsrc, o, ip, act, smem, inArow, inBrow, acc);
  else if (seg == 1)
    sconv_acc_p<O, I, SPL, NSEG, NIP, TW, 1>(wsrc, o, ip, act, smem, inArow, inBrow, acc);
  else if constexpr (NSEG > 2) {
    sconv_acc_p<O, I, SPL, NSEG, NIP, TW, 2>(wsrc, o, ip, act, smem, inArow, inBrow, acc);
  }
  if constexpr (NIP >= 2) {
#pragma unroll
    for (int k = 0; k < NC; ++k) acc[k] += __shfl_xor(acc[k], 1);
  }
  if constexpr (NIP >= 4) {
#pragma unroll
    for (int k = 0; k < NC; ++k) acc[k] += __shfl_xor(acc[k], 2);
  }
  __syncthreads();  // all reads done before overwriting rows
  if (act && ip == 0) {
    if (seg == 0) sconv_write_p<NSEG, 0>(smem, outrow, o, acc);
    else if (seg == 1) sconv_write_p<NSEG, 1>(smem, outrow, o, acc);
    else if constexpr (NSEG > 2) { sconv_write_p<NSEG, 2>(smem, outrow, o, acc); }
  }
  __syncthreads();
}

// ---------------- prep: bake fp16 A-fragments + paired fp16 sconv weights into ws
__global__ void scnn_prep(const float* __restrict__ sft, const float* __restrict__ isft,
                          const float* __restrict__ w1, const float* __restrict__ w2,
                          const float* __restrict__ w3, const float* __restrict__ w4,
                          const float* __restrict__ w5, const float* __restrict__ w6,
                          const float* __restrict__ w7, const float* __restrict__ w8,
                          const float* __restrict__ w9, u32* __restrict__ wsbuf) {
  const int gid = blockIdx.x * 256 + threadIdx.x;
  if (gid < 3584) {  // A1 frags
    const int f = gid >> 8, r = gid & 255, ln = r >> 2, wd = r & 3;
    const int mt = f >> 1, kt = f & 1;
    const int d = 16 * mt + (ln & 15);
    const int c = 32 * kt + 8 * (ln >> 4) + 2 * wd;
    const float v0 = (d < 100 && c < 45) ? isft[d * 45 + c] : 0.f;
    const float v1 = (d < 100 && c + 1 < 45) ? isft[d * 45 + c + 1] : 0.f;
    wsbuf[gid] = pk2rne(v0, v1);
  } else if (gid < WS_FRAG_U32) {  // A2 frags
    const int e = gid - 3584;
    const int f = e >> 8, r = e & 255, ln = r >> 2, wd = r & 3;
    const int mt = f >> 2, kt = f & 3;
    const int c = 16 * mt + (ln & 15);
    const int d = 32 * kt + 8 * (ln >> 4) + 2 * wd;
    const float v0 = (c < 45 && d < 100) ? sft[c * 100 + d] : 0.f;
    const float v1 = (c < 45 && d + 1 < 100) ? sft[c * 100 + d + 1] : 0.f;
    wsbuf[gid] = pk2rne(v0, v1);
  } else if (gid < WS_FRAG_U32 + WP_U32) {  // paired weights: [p][l][o] u32
    const int e = gid - WS_FRAG_U32;
    const float* src; int I, O, off;
    if (e < 160)        { src = w1; I = 4;   O = 16;  off = 0; }
    else if (e < 1440)  { src = w2; I = 16;  O = 32;  off = 160; }
    else if (e < 6560)  { src = w3; I = 32;  O = 64;  off = 1440; }
    else if (e < 27040) { src = w4; I = 64;  O = 128; off = 6560; }
    else if (e < 47520) { src = w5; I = 128; O = 64;  off = 27040; }
    else if (e < 57760) { src = w6; I = 128; O = 32;  off = 47520; }
    else if (e < 60320) { src = w7; I = 64;  O = 16;  off = 57760; }
    else if (e < 61600) { src = w8; I = 32;  O = 16;  off = 60320; }
    else                { src = w9; I = 16;  O = 1;   off = 61600; }
    const int e2 = e - off;
    const int p = e2 / (5 * O), l = (e2 / O) % 5, o = e2 % O;
    wsbuf[e + WS_FRAG_U32] = pk2rne(src[(o * I + 2 * p) * 5 + l], src[(o * I + 2 * p + 1) * 5 + l]);
  }
}

// ---------------- main fused kernel
template <bool TW>
__global__ __launch_bounds__(256, 2) void scnn_mfma(
    const float* __restrict__ x, const float* __restrict__ sft, const float* __restrict__ isft,
    const float* __restrict__ w1, const float* __restrict__ w2, const float* __restrict__ w3,
    const float* __restrict__ w4, const float* __restrict__ w5, const float* __restrict__ w6,
    const float* __restrict__ w7, const float* __restrict__ w8, const float* __restrict__ w9,
    const u32* __restrict__ wsbuf, float* __restrict__ out) {
  __shared__ __align__(16) char smem[NPAIRS * PRB];
  const int tid = threadIdx.x, lane = tid & 63, wid = tid >> 6, b = blockIdx.x;
  const u32* wp = TW ? (wsbuf + WS_FRAG_U32) : nullptr;

  Frags F;
  if constexpr (TW) {
    const uint4* p1 = (const uint4*)wsbuf;
#pragma unroll
    for (int f = 0; f < 14; ++f)
      F.a1[f / 2][f % 2] = __builtin_bit_cast(f16x8, p1[f * 64 + lane]);
    const uint4* p2 = p1 + 14 * 64;
#pragma unroll
    for (int f = 0; f < 12; ++f)
      F.a2[f / 4][f % 4] = __builtin_bit_cast(f16x8, p2[f * 64 + lane]);
  } else {
    const int i15 = lane & 15, g = lane >> 4;
#pragma unroll
    for (int mt = 0; mt < 7; ++mt)
#pragma unroll
      for (int kt = 0; kt < 2; ++kt) {
        const int d = 16 * mt + i15;
        f16x8 v;
#pragma unroll
        for (int j = 0; j < 8; ++j) {
          const int c = 32 * kt + 8 * g + j;
          v[j] = (half_t)((d < 100 && c < 45) ? isft[d * 45 + c] : 0.f);
        }
        F.a1[mt][kt] = v;
      }
#pragma unroll
    for (int mt = 0; mt < 3; ++mt)
#pragma unroll
      for (int kt = 0; kt < 4; ++kt) {
        const int c = 16 * mt + i15;
        f16x8 v;
#pragma unroll
        for (int j = 0; j < 8; ++j) {
          const int d = 32 * kt + 8 * g + j;
          v[j] = (half_t)((c < 45 && d < 100) ? sft[c * 100 + d] : 0.f);
        }
        F.a2[mt][kt] = v;
      }
  }

  // zero pad region of every pair row: bytes 192..272 (c = 48..63 + slack).
  // Writes below never touch c >= 48, so this stays zero for the whole kernel.
  for (int idx = tid; idx < NPAIRS * 20; idx += 256) {
    const int pr = idx / 20, w = idx % 20;
    *(u32*)(smem + pr * PRB + 192 + w * 4) = 0u;
  }
  // stage x [4,45] -> rows 0..3 (paired layout), pads c=45..47 zeroed
  if (tid < 192) {
    const int r = tid / 48, c = tid % 48;
    const float v = (c < 45) ? x[b * 180 + r * 45 + c] : 0.f;
    *(half_t*)(smem + (r >> 1) * PRB + c * 4 + (r & 1) * 2) = (half_t)v;
  }
  __syncthreads();

  sconv_layer<16, 4, 4, 3, 4, TW>(TW ? (const void*)(wp + 0) : (const void*)w1, smem, tid, 0, 0, 0);
  nonlin_tiles(F, smem, lane, wid, 1, 1, 0, 0, E1R, E1R);            // e1
  __syncthreads();
  sconv_layer<32, 16, 16, 2, 4, TW>(TW ? (const void*)(wp + 160) : (const void*)w2, smem, tid, E1R, E1R, 0);
  nonlin_tiles(F, smem, lane, wid, 2, 2, 0, 0, E2R, E2R);            // e2
  __syncthreads();
  sconv_layer<64, 32, 32, 2, 2, TW>(TW ? (const void*)(wp + 1440) : (const void*)w3, smem, tid, E2R, E2R, 0);
  nonlin_tiles(F, smem, lane, wid, 4, 4, 0, 0, E3R, E3R);            // e3
  __syncthreads();
  sconv_layer<128, 64, 64, 2, 1, TW>(TW ? (const void*)(wp + 6560) : (const void*)w4, smem, tid, E3R, E3R, 0);
  nonlin_tiles(F, smem, lane, wid, 8, 8, 0, 0, 0, 0);                // e4 in place (rows 0..127)
  __syncthreads();
  sconv_layer<64, 128, 128, 2, 2, TW>(TW ? (const void*)(wp + 27040) : (const void*)w5, smem, tid, 0, 0, 0);  // F -> rows 0..63
  nonlin_tiles(F, smem, lane, wid, 8, 4, 0, E3R, 0, E3R);            // d1 = nonlin([F;e3]) in place
  __syncthreads();
  sconv_layer<32, 128, 64, 2, 4, TW>(TW ? (const void*)(wp + 47520) : (const void*)w6, smem, tid, 0, E3R, 0); // G -> rows 0..31
  nonlin_tiles(F, smem, lane, wid, 4, 2, 0, E2R, 0, E2R);            // d2 = nonlin([G;e2]) in place
  __syncthreads();
  sconv_layer<16, 64, 32, 3, 4, TW>(TW ? (const void*)(wp + 57760) : (const void*)w7, smem, tid, 0, E2R, 0);  // H -> rows 0..15
  nonlin_tiles(F, smem, lane, wid, 2, 1, 0, E1R, 0, E1R);            // d3 = nonlin([H;e1]) in place
  __syncthreads();
  sconv_layer<16, 32, 16, 3, 4, TW>(TW ? (const void*)(wp + 60320) : (const void*)w8, smem, tid, 0, E1R, 0);  // t8 -> rows 0..15
  nonlin_tiles(F, smem, lane, wid, 1, 1, 0, 0, 0, 0);                // d4 in place (rows 0..15)
  __syncthreads();

  // final sconv: O=1, I=16 (d4 rows 0..15) -> out[b,c] fp32
  if (tid < 45) {
    const int c = tid, l = l_of(c);
    float acc = 0.f;
#pragma unroll
    for (int i = 0; i < 16; ++i)
      acc += w9[i * 5 + l] *
             (float)(*(const half_t*)(smem + (i >> 1) * PRB + c * 4 + (i & 1) * 2));
    out[b * 45 + c] = acc * lfac_of(l);
  }
}

extern "C" void kernel_launch(void* const* d_in, const int* in_sizes, int n_in,
                              void* d_out, int out_size, void* d_ws, size_t ws_size,
                              hipStream_t stream) {
  (void)n_in; (void)out_size;
  const float* x    = (const float*)d_in[0];
  const float* sft  = (const float*)d_in[1];
  const float* isft = (const float*)d_in[2];
  const float* w1 = (const float*)d_in[3];
  const float* w2 = (const float*)d_in[4];
  const float* w3 = (const float*)d_in[5];
  const float* w4 = (const float*)d_in[6];
  const float* w5 = (const float*)d_in[7];
  const float* w6 = (const float*)d_in[8];
  const float* w7 = (const float*)d_in[9];
  const float* w8 = (const float*)d_in[10];
  const float* w9 = (const float*)d_in[11];
  float* out = (float*)d_out;

  const int batch = in_sizes[0] / 180;  // 16384

  if (ws_size >= (size_t)WS_NEEDED) {
    u32* wsbuf = (u32*)d_ws;
    const int prepN = WS_FRAG_U32 + WP_U32;
    hipLaunchKernelGGL(scnn_prep, dim3((prepN + 255) / 256), dim3(256), 0, stream,
                       sft, isft, w1, w2, w3, w4, w5, w6, w7, w8, w9, wsbuf);
    hipLaunchKernelGGL((scnn_mfma<true>), dim3(batch), dim3(256), 0, stream,
                       x, sft, isft, w1, w2, w3, w4, w5, w6, w7, w8, w9, wsbuf, out);
  } else {
    hipLaunchKernelGGL((scnn_mfma<false>), dim3(batch), dim3(256), 0, stream,
                       x, sft, isft, w1, w2, w3, w4, w5, w6, w7, w8, w9,
                       (const u32*)nullptr, out);
  }
}

// Round 8
// 1635.991 us; speedup vs baseline: 9.0207x; 1.0943x over previous
//
#include <hip/hip_runtime.h>
#include <math.h>

// SCNN fused, round 8: free ~48 VGPRs by streaming the GEMM2 A-fragments (a2)
// from the pre-baked ws table per (m,kt) instead of keeping them resident.
// launch_bounds (256,3) (cap 170 regs, actual ~110-130 -> 3-4 waves/SIMD).
// Everything else identical to round 7 (verified).

typedef _Float16 half_t;
typedef _Float16 f16x8 __attribute__((ext_vector_type(8)));
typedef __fp16 h2 __attribute__((ext_vector_type(2)));
typedef float f32x4 __attribute__((ext_vector_type(4)));
typedef unsigned int u32;

#define PRB 272    // bytes per pair-row: 64 c * 4B + 16 slack; 272/4 % 32 == 4 -> conflict-free
#define NPAIRS 120 // 240 logical rows
#define E1R 128
#define E2R 144
#define E3R 176

// ws layout (u32): [0,3584) A1 frags, [3584,6656) A2 frags, [6656, +61640) paired weights
#define WS_FRAG_U32 6656
#define WP_U32 61640
#define WS_NEEDED ((WS_FRAG_U32 + WP_U32) * 4)

__device__ __host__ __forceinline__ constexpr int l_of(int c) {
  return (c >= 1) + (c >= 6) + (c >= 15) + (c >= 28);
}
__device__ __forceinline__ float lfac_of(int l) {
  return sqrtf(3.14159265358979323846f / (float)(4 * l + 1));
}
// RTZ pack (hardware v_cvt_pkrtz) — hot path, round-4-verified numerics
__device__ __forceinline__ u32 pk2(float a, float b) {
  auto v = __builtin_amdgcn_cvt_pkrtz(a, b);
  return __builtin_bit_cast(u32, v);
}
// RNE pack — for weight/frag baking (cold path, better rounding)
__device__ __forceinline__ u32 pk2rne(float a, float b) {
  unsigned short lo = __builtin_bit_cast(unsigned short, (half_t)a);
  unsigned short hi = __builtin_bit_cast(unsigned short, (half_t)b);
  return (u32)lo | ((u32)hi << 16);
}
// D = S0.x*S1.x + S0.y*S1.y + S2  (fp16 mul, fp32 accumulate)
__device__ __forceinline__ float dot2(u32 xp, u32 wp, float acc) {
#if __has_builtin(__builtin_amdgcn_fdot2)
  return __builtin_amdgcn_fdot2(__builtin_bit_cast(h2, xp), __builtin_bit_cast(h2, wp), acc, false);
#else
  h2 xv = __builtin_bit_cast(h2, xp), wv = __builtin_bit_cast(h2, wp);
  return acc + (float)xv[0] * (float)wv[0] + (float)xv[1] * (float)wv[1];
#endif
}
// a = dword at col c (lo16=row_even[c], hi16=row_odd[c]), b = same at c+1.
// Returns [row_par[c], row_par[c+1]] as two fp16 in one dword. Portable ops.
__device__ __forceinline__ u32 mergepair(u32 a, u32 b, int par) {
  return par ? ((a >> 16) | (b & 0xffff0000u))
             : ((a & 0x0000ffffu) | (b << 16));
}
__device__ __forceinline__ f32x4 mfma16(f16x8 a, f16x8 b, f32x4 c) {
  return __builtin_amdgcn_mfma_f32_16x16x32_f16(a, b, c, 0, 0, 0);
}

struct Frags {
  f16x8 a1[7][2];  // isft: d = 16*mt + (l&15), k=c = 32*kt + 8*(l>>4) + j (0 pad)
};

// read 8 consecutive-c fp16 of row parity par from a pair-row base (c0 8-aligned)
__device__ __forceinline__ f16x8 ldpair8(const char* base, int par) {
  const uint4 q0 = *(const uint4*)(base);
  const uint4 q1 = *(const uint4*)(base + 16);
  uint4 r;
  r.x = mergepair(q0.x, q0.y, par);
  r.y = mergepair(q0.z, q0.w, par);
  r.z = mergepair(q1.x, q1.y, par);
  r.w = mergepair(q1.z, q1.w, par);
  return __builtin_bit_cast(f16x8, r);
}

// ---------------- nonlin: out[r,c] = sum_d sft[c,d] * relu(sum_c' isft[d,c'] in[r,c'])
// a2 fragments streamed from p2 (L1-hot 3KB table) per (m,kt) — not register-resident.
template <bool TW>
__device__ void nonlin_tiles(const Frags& F, const uint4* __restrict__ p2,
                             const float* __restrict__ sft,
                             char* smem, int lane, int wid,
                             int T, int TA, int inArow, int inBrow,
                             int outArow, int outBrow) {
  const int i15 = lane & 15, g = lane >> 4;
  for (int t = wid; t < T; t += 4) {
    const int inrow = (t < TA) ? (inArow + t * 16) : (inBrow + (t - TA) * 16);
    const int outrow = (t < TA) ? (outArow + t * 16) : (outBrow + (t - TA) * 16);
    const int R = inrow + i15, par = R & 1;
    const char* ib = smem + (R >> 1) * PRB + g * 32;
    f16x8 b0 = ldpair8(ib, par);        // c = 8g + j
    f16x8 b1 = ldpair8(ib + 128, par);  // c = 32 + 8g + j  (c>=48 zeroed pad)
    f32x4 acc1[7];
#pragma unroll
    for (int mt = 0; mt < 7; ++mt) {
      f32x4 z = {0.f, 0.f, 0.f, 0.f};
      z = mfma16(F.a1[mt][0], b0, z);
      acc1[mt] = mfma16(F.a1[mt][1], b1, z);
    }
    // relu + pack: pk[mt][q] = fp16 pair for d = 16*mt + 4*g + {2q, 2q+1}
    u32 pk[7][2];
#pragma unroll
    for (int mt = 0; mt < 7; ++mt) {
      pk[mt][0] = pk2(fmaxf(acc1[mt][0], 0.f), fmaxf(acc1[mt][1], 0.f));
      pk[mt][1] = pk2(fmaxf(acc1[mt][2], 0.f), fmaxf(acc1[mt][3], 0.f));
    }
    // GEMM2: B2 word p of kt holds d = 32*kt + 8*g + {2p,2p+1}, gathered cross-lane
    f32x4 acc2[3];
#pragma unroll
    for (int m = 0; m < 3; ++m) acc2[m] = (f32x4){0.f, 0.f, 0.f, 0.f};
    const int srcBase = i15 + 32 * (g & 1);
    const bool sLow = (g < 2);
#pragma unroll
    for (int kt = 0; kt < 4; ++kt) {
      u32 wv[4];
#pragma unroll
      for (int p = 0; p < 4; ++p) {
        const int src = srcBase + 16 * (p >> 1);
        u32 vA = (u32)__shfl((int)pk[2 * kt][p & 1], src);
        u32 vB = 0u;
        if (kt < 3) vB = (u32)__shfl((int)pk[2 * kt + 1][p & 1], src);  // kt==3: d>=112 -> 0
        wv[p] = sLow ? vA : vB;
      }
      uint4 w4; w4.x = wv[0]; w4.y = wv[1]; w4.z = wv[2]; w4.w = wv[3];
      f16x8 b2 = __builtin_bit_cast(f16x8, w4);
#pragma unroll
      for (int m = 0; m < 3; ++m) {
        f16x8 a2;
        if constexpr (TW) {
          a2 = __builtin_bit_cast(f16x8, p2[(m * 4 + kt) * 64 + lane]);  // streamed, L1-hot
        } else {
          const int c0 = 16 * m + i15;
          f16x8 v;
#pragma unroll
          for (int j = 0; j < 8; ++j) {
            const int d = 32 * kt + 8 * g + j;
            v[j] = (half_t)((c0 < 45 && d < 100) ? sft[c0 * 100 + d] : 0.f);
          }
          a2 = v;
        }
        acc2[m] = mfma16(a2, b2, acc2[m]);
      }
    }
    // write: row Ro = outrow + i15, cols c = 16*m + 4*g + j (16-bit stores, paired layout)
    const int Ro = outrow + i15;
    char* ob = smem + (Ro >> 1) * PRB + (Ro & 1) * 2 + g * 16;
#pragma unroll
    for (int m = 0; m < 3; ++m)
#pragma unroll
      for (int j = 0; j < 4; ++j)
        *(half_t*)(ob + m * 64 + j * 4) = (half_t)acc2[m][j];
  }
}

// ---------------- sconv via v_dot2: out[o,c] = lfac(c) * sum_i w[o,i,l(c)] * in[i,c]
template <int O, int I, int SPL, int NSEG, int NIP, bool TW, int SEG>
__device__ __forceinline__ void sconv_acc_p(const void* __restrict__ wsrc, int o, int ip,
                                            bool act, const char* smem, int inArow, int inBrow,
                                            float* acc) {
  constexpr int NC = 48 / NSEG;
  constexpr int NU4 = NC / 4;
  constexpr int C0 = SEG * NC;
#pragma unroll
  for (int k = 0; k < NC; ++k) acc[k] = 0.f;
  if (!act) return;
  const u32* __restrict__ wp = (const u32*)wsrc;
  const float* __restrict__ wf = (const float*)wsrc;
#pragma unroll 2
  for (int p = ip; p < I / 2; p += NIP) {
    const int rA = 2 * p;
    const char* rb = smem +
        (((rA < SPL) ? ((inArow >> 1) + p) : ((inBrow >> 1) + p - SPL / 2)) * PRB) + C0 * 4;
    u32 wv[5];
    if constexpr (TW) {
#pragma unroll
      for (int l = 0; l < 5; ++l) wv[l] = wp[(p * 5 + l) * O + o];  // coalesced over o
    } else {
#pragma unroll
      for (int l = 0; l < 5; ++l)
        wv[l] = pk2rne(wf[(o * I + rA) * 5 + l], wf[(o * I + rA + 1) * 5 + l]);
    }
#pragma unroll
    for (int k = 0; k < NU4; ++k) {
      const uint4 q = *(const uint4*)(rb + k * 16);  // 4 c's, both rows of the pair
      const u32 qq[4] = {q.x, q.y, q.z, q.w};
#pragma unroll
      for (int j = 0; j < 4; ++j) {
        const int c = C0 + k * 4 + j;
        acc[k * 4 + j] = dot2(qq[j], wv[l_of(c)], acc[k * 4 + j]);
      }
    }
  }
}

template <int NSEG, int SEG>
__device__ __forceinline__ void sconv_write_p(char* smem, int outrow, int o, const float* acc) {
  constexpr int NC = 48 / NSEG;
  constexpr int C0 = SEG * NC;
  const int R = outrow + o;
  char* wb = smem + (R >> 1) * PRB + (R & 1) * 2 + C0 * 4;
#pragma unroll
  for (int k = 0; k < NC; ++k) {
    const int c = C0 + k;
    *(half_t*)(wb + k * 4) = (half_t)(acc[k] * lfac_of(l_of(c)));
  }
}

template <int O, int I, int SPL, int NSEG, int NIP, bool TW>
__device__ void sconv_layer(const void* __restrict__ wsrc, char* smem, int tid,
                            int inArow, int inBrow, int outrow) {
  constexpr int NC = 48 / NSEG;
  const int ip = (NIP == 1) ? 0 : (tid % NIP);
  const int seg = (tid / NIP) % NSEG;
  const int o = tid / (NIP * NSEG);
  const bool act = (o < O);
  float acc[NC];
  if (seg == 0)
    sconv_acc_p<O, I, SPL, NSEG, NIP, TW, 0>(wsrc, o, ip, act, smem, inArow, inBrow, acc);
  else if (seg == 1)
    sconv_acc_p<O, I, SPL, NSEG, NIP, TW, 1>(wsrc, o, ip, act, smem, inArow, inBrow, acc);
  else if constexpr (NSEG > 2) {
    sconv_acc_p<O, I, SPL, NSEG, NIP, TW, 2>(wsrc, o, ip, act, smem, inArow, inBrow, acc);
  }
  if constexpr (NIP >= 2) {
#pragma unroll
    for (int k = 0; k < NC; ++k) acc[k] += __shfl_xor(acc[k], 1);
  }
  if constexpr (NIP >= 4) {
#pragma unroll
    for (int k = 0; k < NC; ++k) acc[k] += __shfl_xor(acc[k], 2);
  }
  __syncthreads();  // all reads done before overwriting rows
  if (act && ip == 0) {
    if (seg == 0) sconv_write_p<NSEG, 0>(smem, outrow, o, acc);
    else if (seg == 1) sconv_write_p<NSEG, 1>(smem, outrow, o, acc);
    else if constexpr (NSEG > 2) { sconv_write_p<NSEG, 2>(smem, outrow, o, acc); }
  }
  __syncthreads();
}

// ---------------- prep: bake fp16 A-fragments + paired fp16 sconv weights into ws
__global__ void scnn_prep(const float* __restrict__ sft, const float* __restrict__ isft,
                          const float* __restrict__ w1, const float* __restrict__ w2,
                          const float* __restrict__ w3, const float* __restrict__ w4,
                          const float* __restrict__ w5, const float* __restrict__ w6,
                          const float* __restrict__ w7, const float* __restrict__ w8,
                          const float* __restrict__ w9, u32* __restrict__ wsbuf) {
  const int gid = blockIdx.x * 256 + threadIdx.x;
  if (gid < 3584) {  // A1 frags
    const int f = gid >> 8, r = gid & 255, ln = r >> 2, wd = r & 3;
    const int mt = f >> 1, kt = f & 1;
    const int d = 16 * mt + (ln & 15);
    const int c = 32 * kt + 8 * (ln >> 4) + 2 * wd;
    const float v0 = (d < 100 && c < 45) ? isft[d * 45 + c] : 0.f;
    const float v1 = (d < 100 && c + 1 < 45) ? isft[d * 45 + c + 1] : 0.f;
    wsbuf[gid] = pk2rne(v0, v1);
  } else if (gid < WS_FRAG_U32) {  // A2 frags
    const int e = gid - 3584;
    const int f = e >> 8, r = e & 255, ln = r >> 2, wd = r & 3;
    const int mt = f >> 2, kt = f & 3;
    const int c = 16 * mt + (ln & 15);
    const int d = 32 * kt + 8 * (ln >> 4) + 2 * wd;
    const float v0 = (c < 45 && d < 100) ? sft[c * 100 + d] : 0.f;
    const float v1 = (c < 45 && d + 1 < 100) ? sft[c * 100 + d + 1] : 0.f;
    wsbuf[gid] = pk2rne(v0, v1);
  } else if (gid < WS_FRAG_U32 + WP_U32) {  // paired weights: [p][l][o] u32
    const int e = gid - WS_FRAG_U32;
    const float* src; int I, O, off;
    if (e < 160)        { src = w1; I = 4;   O = 16;  off = 0; }
    else if (e < 1440)  { src = w2; I = 16;  O = 32;  off = 160; }
    else if (e < 6560)  { src = w3; I = 32;  O = 64;  off = 1440; }
    else if (e < 27040) { src = w4; I = 64;  O = 128; off = 6560; }
    else if (e < 47520) { src = w5; I = 128; O = 64;  off = 27040; }
    else if (e < 57760) { src = w6; I = 128; O = 32;  off = 47520; }
    else if (e < 60320) { src = w7; I = 64;  O = 16;  off = 57760; }
    else if (e < 61600) { src = w8; I = 32;  O = 16;  off = 60320; }
    else                { src = w9; I = 16;  O = 1;   off = 61600; }
    const int e2 = e - off;
    const int p = e2 / (5 * O), l = (e2 / O) % 5, o = e2 % O;
    wsbuf[e + WS_FRAG_U32] = pk2rne(src[(o * I + 2 * p) * 5 + l], src[(o * I + 2 * p + 1) * 5 + l]);
  }
}

// ---------------- main fused kernel
template <bool TW>
__global__ __launch_bounds__(256, 3) void scnn_mfma(
    const float* __restrict__ x, const float* __restrict__ sft, const float* __restrict__ isft,
    const float* __restrict__ w1, const float* __restrict__ w2, const float* __restrict__ w3,
    const float* __restrict__ w4, const float* __restrict__ w5, const float* __restrict__ w6,
    const float* __restrict__ w7, const float* __restrict__ w8, const float* __restrict__ w9,
    const u32* __restrict__ wsbuf, float* __restrict__ out) {
  __shared__ __align__(16) char smem[NPAIRS * PRB];
  const int tid = threadIdx.x, lane = tid & 63, wid = tid >> 6, b = blockIdx.x;
  const u32* wp = TW ? (wsbuf + WS_FRAG_U32) : nullptr;
  const uint4* p2 = TW ? ((const uint4*)wsbuf) + 14 * 64 : nullptr;  // A2 frag table

  Frags F;
  if constexpr (TW) {
    const uint4* p1 = (const uint4*)wsbuf;
#pragma unroll
    for (int f = 0; f < 14; ++f)
      F.a1[f / 2][f % 2] = __builtin_bit_cast(f16x8, p1[f * 64 + lane]);
  } else {
    const int i15 = lane & 15, g = lane >> 4;
#pragma unroll
    for (int mt = 0; mt < 7; ++mt)
#pragma unroll
      for (int kt = 0; kt < 2; ++kt) {
        const int d = 16 * mt + i15;
        f16x8 v;
#pragma unroll
        for (int j = 0; j < 8; ++j) {
          const int c = 32 * kt + 8 * g + j;
          v[j] = (half_t)((d < 100 && c < 45) ? isft[d * 45 + c] : 0.f);
        }
        F.a1[mt][kt] = v;
      }
  }

  // zero pad region of every pair row: bytes 192..272 (c = 48..63 + slack).
  // Writes below never touch c >= 48, so this stays zero for the whole kernel.
  for (int idx = tid; idx < NPAIRS * 20; idx += 256) {
    const int pr = idx / 20, w = idx % 20;
    *(u32*)(smem + pr * PRB + 192 + w * 4) = 0u;
  }
  // stage x [4,45] -> rows 0..3 (paired layout), pads c=45..47 zeroed
  if (tid < 192) {
    const int r = tid / 48, c = tid % 48;
    const float v = (c < 45) ? x[b * 180 + r * 45 + c] : 0.f;
    *(half_t*)(smem + (r >> 1) * PRB + c * 4 + (r & 1) * 2) = (half_t)v;
  }
  __syncthreads();

  sconv_layer<16, 4, 4, 3, 4, TW>(TW ? (const void*)(wp + 0) : (const void*)w1, smem, tid, 0, 0, 0);
  nonlin_tiles<TW>(F, p2, sft, smem, lane, wid, 1, 1, 0, 0, E1R, E1R);            // e1
  __syncthreads();
  sconv_layer<32, 16, 16, 2, 4, TW>(TW ? (const void*)(wp + 160) : (const void*)w2, smem, tid, E1R, E1R, 0);
  nonlin_tiles<TW>(F, p2, sft, smem, lane, wid, 2, 2, 0, 0, E2R, E2R);            // e2
  __syncthreads();
  sconv_layer<64, 32, 32, 2, 2, TW>(TW ? (const void*)(wp + 1440) : (const void*)w3, smem, tid, E2R, E2R, 0);
  nonlin_tiles<TW>(F, p2, sft, smem, lane, wid, 4, 4, 0, 0, E3R, E3R);            // e3
  __syncthreads();
  sconv_layer<128, 64, 64, 2, 1, TW>(TW ? (const void*)(wp + 6560) : (const void*)w4, smem, tid, E3R, E3R, 0);
  nonlin_tiles<TW>(F, p2, sft, smem, lane, wid, 8, 8, 0, 0, 0, 0);                // e4 in place (rows 0..127)
  __syncthreads();
  sconv_layer<64, 128, 128, 2, 2, TW>(TW ? (const void*)(wp + 27040) : (const void*)w5, smem, tid, 0, 0, 0);  // F -> rows 0..63
  nonlin_tiles<TW>(F, p2, sft, smem, lane, wid, 8, 4, 0, E3R, 0, E3R);            // d1 = nonlin([F;e3]) in place
  __syncthreads();
  sconv_layer<32, 128, 64, 2, 4, TW>(TW ? (const void*)(wp + 47520) : (const void*)w6, smem, tid, 0, E3R, 0); // G -> rows 0..31
  nonlin_tiles<TW>(F, p2, sft, smem, lane, wid, 4, 2, 0, E2R, 0, E2R);            // d2 = nonlin([G;e2]) in place
  __syncthreads();
  sconv_layer<16, 64, 32, 3, 4, TW>(TW ? (const void*)(wp + 57760) : (const void*)w7, smem, tid, 0, E2R, 0);  // H -> rows 0..15
  nonlin_tiles<TW>(F, p2, sft, smem, lane, wid, 2, 1, 0, E1R, 0, E1R);            // d3 = nonlin([H;e1]) in place
  __syncthreads();
  sconv_layer<16, 32, 16, 3, 4, TW>(TW ? (const void*)(wp + 60320) : (const void*)w8, smem, tid, 0, E1R, 0);  // t8 -> rows 0..15
  nonlin_tiles<TW>(F, p2, sft, smem, lane, wid, 1, 1, 0, 0, 0, 0);                // d4 in place (rows 0..15)
  __syncthreads();

  // final sconv: O=1, I=16 (d4 rows 0..15) -> out[b,c] fp32
  if (tid < 45) {
    const int c = tid, l = l_of(c);
    float acc = 0.f;
#pragma unroll
    for (int i = 0; i < 16; ++i)
      acc += w9[i * 5 + l] *
             (float)(*(const half_t*)(smem + (i >> 1) * PRB + c * 4 + (i & 1) * 2));
    out[b * 45 + c] = acc * lfac_of(l);
  }
}

extern "C" void kernel_launch(void* const* d_in, const int* in_sizes, int n_in,
                              void* d_out, int out_size, void* d_ws, size_t ws_size,
                              hipStream_t stream) {
  (void)n_in; (void)out_size;
  const float* x    = (const float*)d_in[0];
  const float* sft  = (const float*)d_in[1];
  const float* isft = (const float*)d_in[2];
  const float* w1 = (const float*)d_in[3];
  const float* w2 = (const float*)d_in[4];
  const float* w3 = (const float*)d_in[5];
  const float* w4 = (const float*)d_in[6];
  const float* w5 = (const float*)d_in[7];
  const float* w6 = (const float*)d_in[8];
  const float* w7 = (const float*)d_in[9];
  const float* w8 = (const float*)d_in[10];
  const float* w9 = (const float*)d_in[11];
  float* out = (float*)d_out;

  const int batch = in_sizes[0] / 180;  // 16384

  if (ws_size >= (size_t)WS_NEEDED) {
    u32* wsbuf = (u32*)d_ws;
    const int prepN = WS_FRAG_U32 + WP_U32;
    hipLaunchKernelGGL(scnn_prep, dim3((prepN + 255) / 256), dim3(256), 0, stream,
                       sft, isft, w1, w2, w3, w4, w5, w6, w7, w8, w9, wsbuf);
    hipLaunchKernelGGL((scnn_mfma<true>), dim3(batch), dim3(256), 0, stream,
                       x, sft, isft, w1, w2, w3, w4, w5, w6, w7, w8, w9, wsbuf, out);
  } else {
    hipLaunchKernelGGL((scnn_mfma<false>), dim3(batch), dim3(256), 0, stream,
                       x, sft, isft, w1, w2, w3, w4, w5, w6, w7, w8, w9,
                       (const u32*)nullptr, out);
  }
}

// Round 9
// 713.853 us; speedup vs baseline: 20.6735x; 2.2918x over previous
//
#include <hip/hip_runtime.h>
#include <math.h>

// SCNN fused, round 9: sconv moved to MFMA (per-l-group GEMMs, A-frags pre-baked
// with lfac folded; B read straight from pair-interleaved LDS; masked writes).
// nonlin MFMA path unchanged (verified r4-r8). dot2 path kept as no-ws fallback.

typedef _Float16 half_t;
typedef _Float16 f16x8 __attribute__((ext_vector_type(8)));
typedef __fp16 h2 __attribute__((ext_vector_type(2)));
typedef float f32x4 __attribute__((ext_vector_type(4)));
typedef unsigned int u32;

#define PRB 272    // bytes per pair-row: 64 c * 4B + 16 slack; 272/4 % 32 == 4 -> conflict-free
#define NPAIRS 120 // 240 logical rows
#define E1R 128
#define E2R 144
#define E3R 176

// ws layout (u32): [0,3584) A1 frags, [3584,6656) A2 frags, [6656,+64000) sconv A-frags
#define WS_FRAG_U32 6656
#define WS_AFRAG_U32 64000
#define WS_NEEDED ((WS_FRAG_U32 + WS_AFRAG_U32) * 4)

__device__ __host__ __forceinline__ constexpr int l_of(int c) {
  return (c >= 1) + (c >= 6) + (c >= 15) + (c >= 28);
}
__device__ __forceinline__ float lfac_of(int l) {
  return sqrtf(3.14159265358979323846f / (float)(4 * l + 1));
}
__device__ __forceinline__ u32 pk2(float a, float b) {
  auto v = __builtin_amdgcn_cvt_pkrtz(a, b);
  return __builtin_bit_cast(u32, v);
}
__device__ __forceinline__ u32 pk2rne(float a, float b) {
  unsigned short lo = __builtin_bit_cast(unsigned short, (half_t)a);
  unsigned short hi = __builtin_bit_cast(unsigned short, (half_t)b);
  return (u32)lo | ((u32)hi << 16);
}
__device__ __forceinline__ float dot2(u32 xp, u32 wp, float acc) {
#if __has_builtin(__builtin_amdgcn_fdot2)
  return __builtin_amdgcn_fdot2(__builtin_bit_cast(h2, xp), __builtin_bit_cast(h2, wp), acc, false);
#else
  h2 xv = __builtin_bit_cast(h2, xp), wv = __builtin_bit_cast(h2, wp);
  return acc + (float)xv[0] * (float)wv[0] + (float)xv[1] * (float)wv[1];
#endif
}
__device__ __forceinline__ u32 mergepair(u32 a, u32 b, int par) {
  return par ? ((a >> 16) | (b & 0xffff0000u))
             : ((a & 0x0000ffffu) | (b << 16));
}
__device__ __forceinline__ f32x4 mfma16(f16x8 a, f16x8 b, f32x4 c) {
  return __builtin_amdgcn_mfma_f32_16x16x32_f16(a, b, c, 0, 0, 0);
}

struct Frags {
  f16x8 a1[7][2];  // isft: d = 16*mt + (l&15), k=c = 32*kt + 8*(l>>4) + j (0 pad)
};

__device__ __forceinline__ f16x8 ldpair8(const char* base, int par) {
  const uint4 q0 = *(const uint4*)(base);
  const uint4 q1 = *(const uint4*)(base + 16);
  uint4 r;
  r.x = mergepair(q0.x, q0.y, par);
  r.y = mergepair(q0.z, q0.w, par);
  r.z = mergepair(q1.x, q1.y, par);
  r.w = mergepair(q1.z, q1.w, par);
  return __builtin_bit_cast(f16x8, r);
}

// ---------------- nonlin (unchanged from round 8): a2 streamed from ws table
template <bool TW>
__device__ void nonlin_tiles(const Frags& F, const uint4* __restrict__ p2,
                             const float* __restrict__ sft,
                             char* smem, int lane, int wid,
                             int T, int TA, int inArow, int inBrow,
                             int outArow, int outBrow) {
  const int i15 = lane & 15, g = lane >> 4;
  for (int t = wid; t < T; t += 4) {
    const int inrow = (t < TA) ? (inArow + t * 16) : (inBrow + (t - TA) * 16);
    const int outrow = (t < TA) ? (outArow + t * 16) : (outBrow + (t - TA) * 16);
    const int R = inrow + i15, par = R & 1;
    const char* ib = smem + (R >> 1) * PRB + g * 32;
    f16x8 b0 = ldpair8(ib, par);
    f16x8 b1 = ldpair8(ib + 128, par);
    f32x4 acc1[7];
#pragma unroll
    for (int mt = 0; mt < 7; ++mt) {
      f32x4 z = {0.f, 0.f, 0.f, 0.f};
      z = mfma16(F.a1[mt][0], b0, z);
      acc1[mt] = mfma16(F.a1[mt][1], b1, z);
    }
    u32 pk[7][2];
#pragma unroll
    for (int mt = 0; mt < 7; ++mt) {
      pk[mt][0] = pk2(fmaxf(acc1[mt][0], 0.f), fmaxf(acc1[mt][1], 0.f));
      pk[mt][1] = pk2(fmaxf(acc1[mt][2], 0.f), fmaxf(acc1[mt][3], 0.f));
    }
    f32x4 acc2[3];
#pragma unroll
    for (int m = 0; m < 3; ++m) acc2[m] = (f32x4){0.f, 0.f, 0.f, 0.f};
    const int srcBase = i15 + 32 * (g & 1);
    const bool sLow = (g < 2);
#pragma unroll
    for (int kt = 0; kt < 4; ++kt) {
      u32 wv[4];
#pragma unroll
      for (int p = 0; p < 4; ++p) {
        const int src = srcBase + 16 * (p >> 1);
        u32 vA = (u32)__shfl((int)pk[2 * kt][p & 1], src);
        u32 vB = 0u;
        if (kt < 3) vB = (u32)__shfl((int)pk[2 * kt + 1][p & 1], src);
        wv[p] = sLow ? vA : vB;
      }
      uint4 w4; w4.x = wv[0]; w4.y = wv[1]; w4.z = wv[2]; w4.w = wv[3];
      f16x8 b2 = __builtin_bit_cast(f16x8, w4);
#pragma unroll
      for (int m = 0; m < 3; ++m) {
        f16x8 a2;
        if constexpr (TW) {
          a2 = __builtin_bit_cast(f16x8, p2[(m * 4 + kt) * 64 + lane]);
        } else {
          const int c0 = 16 * m + i15;
          f16x8 v;
#pragma unroll
          for (int j = 0; j < 8; ++j) {
            const int d = 32 * kt + 8 * g + j;
            v[j] = (half_t)((c0 < 45 && d < 100) ? sft[c0 * 100 + d] : 0.f);
          }
          a2 = v;
        }
        acc2[m] = mfma16(a2, b2, acc2[m]);
      }
    }
    const int Ro = outrow + i15;
    char* ob = smem + (Ro >> 1) * PRB + (Ro & 1) * 2 + g * 16;
#pragma unroll
    for (int m = 0; m < 3; ++m)
#pragma unroll
      for (int j = 0; j < 4; ++j)
        *(half_t*)(ob + m * 64 + j * 4) = (half_t)acc2[m][j];
  }
}

// ---------------- sconv via MFMA: per l-group GEMM, 6 N-tiles covering 45 cols.
// A-frags pre-baked (lfac folded, zero-padded). INPLACE: hold accs across barrier.
template <int O, int I, int SPL, bool INPLACE>
__device__ void sconv_mfma(const uint4* __restrict__ afr, char* smem,
                           int lane, int wid, int inArow, int inBrow, int outrow) {
  constexpr int Mt = O / 16;
  constexpr int Kt = (I + 31) / 32;
  constexpr int CELLS = Mt * 6;
  constexpr int NCI = (CELLS + 3) / 4;
  constexpr bool CONCAT = (SPL < I);
  const int n15 = lane & 15, g = lane >> 4;

  f32x4 accs[INPLACE ? NCI : 1];

#pragma unroll
  for (int ci = 0; ci < NCI; ++ci) {
    const int cell = wid + 4 * ci;
    if (cell < CELLS) {
      const int mt = cell / 6, grp = cell - 6 * mt;
      const int l = (grp >= 1) + (grp >= 2) + (grp >= 3) + (grp >= 4);
      const int c0 = l * (2 * l - 1) + ((grp == 5) ? 16 : 0);
      const int c = c0 + n15;  // c <= 59 < 64; cols >=45 are zero
      f32x4 acc = {0.f, 0.f, 0.f, 0.f};
#pragma unroll
      for (int kt = 0; kt < Kt; ++kt) {
        const f16x8 A = __builtin_bit_cast(f16x8, afr[((l * Mt + mt) * Kt + kt) * 64 + lane]);
        int basepair;
        if constexpr (CONCAT) {
          const int iA0 = 32 * kt + 8 * g;  // SPL % 8 == 0 -> 8-row span never straddles
          basepair = ((iA0 < SPL) ? (inArow + iA0) : (inBrow + iA0 - SPL)) >> 1;
        } else {
          basepair = (inArow >> 1) + 16 * kt + 4 * g;  // overreads hit zeroed LDS, A zero-padded
        }
        const char* bp = smem + basepair * PRB + c * 4;
        uint4 b4;
        b4.x = *(const u32*)(bp);
        b4.y = *(const u32*)(bp + PRB);
        b4.z = *(const u32*)(bp + 2 * PRB);
        b4.w = *(const u32*)(bp + 3 * PRB);
        acc = mfma16(A, __builtin_bit_cast(f16x8, b4), acc);
      }
      if constexpr (INPLACE) {
        accs[ci] = acc;
      } else {
        const int sz = (grp == 4) ? 16 : (((grp == 0) || (grp == 5)) ? 1 : (4 * l + 1));
        if (n15 < sz) {
          char* wb = smem + ((outrow >> 1) + 8 * mt + 2 * g) * PRB + c * 4;
          *(u32*)(wb) = pk2(acc[0], acc[1]);          // rows 16mt+4g, +1 (pair dword)
          *(u32*)(wb + PRB) = pk2(acc[2], acc[3]);    // rows 16mt+4g+2, +3
        }
      }
    }
  }
  if constexpr (INPLACE) {
    __syncthreads();
#pragma unroll
    for (int ci = 0; ci < NCI; ++ci) {
      const int cell = wid + 4 * ci;
      if (cell < CELLS) {
        const int mt = cell / 6, grp = cell - 6 * mt;
        const int l = (grp >= 1) + (grp >= 2) + (grp >= 3) + (grp >= 4);
        const int c0 = l * (2 * l - 1) + ((grp == 5) ? 16 : 0);
        const int sz = (grp == 4) ? 16 : (((grp == 0) || (grp == 5)) ? 1 : (4 * l + 1));
        const int c = c0 + n15;
        if (n15 < sz) {
          char* wb = smem + ((outrow >> 1) + 8 * mt + 2 * g) * PRB + c * 4;
          *(u32*)(wb) = pk2(accs[ci][0], accs[ci][1]);
          *(u32*)(wb + PRB) = pk2(accs[ci][2], accs[ci][3]);
        }
      }
    }
  }
  __syncthreads();
}

// ---------------- dot2 sconv (no-ws fallback only)
template <int O, int I, int SPL, int NSEG, int NIP, int SEG>
__device__ __forceinline__ void sconv_acc_p(const float* __restrict__ wf, int o, int ip,
                                            bool act, const char* smem, int inArow, int inBrow,
                                            float* acc) {
  constexpr int NC = 48 / NSEG;
  constexpr int NU4 = NC / 4;
  constexpr int C0 = SEG * NC;
#pragma unroll
  for (int k = 0; k < NC; ++k) acc[k] = 0.f;
  if (!act) return;
#pragma unroll 2
  for (int p = ip; p < I / 2; p += NIP) {
    const int rA = 2 * p;
    const char* rb = smem +
        (((rA < SPL) ? ((inArow >> 1) + p) : ((inBrow >> 1) + p - SPL / 2)) * PRB) + C0 * 4;
    u32 wv[5];
#pragma unroll
    for (int l = 0; l < 5; ++l)
      wv[l] = pk2rne(wf[(o * I + rA) * 5 + l], wf[(o * I + rA + 1) * 5 + l]);
#pragma unroll
    for (int k = 0; k < NU4; ++k) {
      const uint4 q = *(const uint4*)(rb + k * 16);
      const u32 qq[4] = {q.x, q.y, q.z, q.w};
#pragma unroll
      for (int j = 0; j < 4; ++j) {
        const int c = C0 + k * 4 + j;
        acc[k * 4 + j] = dot2(qq[j], wv[l_of(c)], acc[k * 4 + j]);
      }
    }
  }
}

template <int NSEG, int SEG>
__device__ __forceinline__ void sconv_write_p(char* smem, int outrow, int o, const float* acc) {
  constexpr int NC = 48 / NSEG;
  constexpr int C0 = SEG * NC;
  const int R = outrow + o;
  char* wb = smem + (R >> 1) * PRB + (R & 1) * 2 + C0 * 4;
#pragma unroll
  for (int k = 0; k < NC; ++k) {
    const int c = C0 + k;
    *(half_t*)(wb + k * 4) = (half_t)(acc[k] * lfac_of(l_of(c)));
  }
}

template <int O, int I, int SPL, int NSEG, int NIP>
__device__ void sconv_layer(const float* __restrict__ wf, char* smem, int tid,
                            int inArow, int inBrow, int outrow) {
  constexpr int NC = 48 / NSEG;
  const int ip = (NIP == 1) ? 0 : (tid % NIP);
  const int seg = (tid / NIP) % NSEG;
  const int o = tid / (NIP * NSEG);
  const bool act = (o < O);
  float acc[NC];
  if (seg == 0)
    sconv_acc_p<O, I, SPL, NSEG, NIP, 0>(wf, o, ip, act, smem, inArow, inBrow, acc);
  else if (seg == 1)
    sconv_acc_p<O, I, SPL, NSEG, NIP, 1>(wf, o, ip, act, smem, inArow, inBrow, acc);
  else if constexpr (NSEG > 2) {
    sconv_acc_p<O, I, SPL, NSEG, NIP, 2>(wf, o, ip, act, smem, inArow, inBrow, acc);
  }
  if constexpr (NIP >= 2) {
#pragma unroll
    for (int k = 0; k < NC; ++k) acc[k] += __shfl_xor(acc[k], 1);
  }
  if constexpr (NIP >= 4) {
#pragma unroll
    for (int k = 0; k < NC; ++k) acc[k] += __shfl_xor(acc[k], 2);
  }
  __syncthreads();
  if (act && ip == 0) {
    if (seg == 0) sconv_write_p<NSEG, 0>(smem, outrow, o, acc);
    else if (seg == 1) sconv_write_p<NSEG, 1>(smem, outrow, o, acc);
    else if constexpr (NSEG > 2) { sconv_write_p<NSEG, 2>(smem, outrow, o, acc); }
  }
  __syncthreads();
}

// ---------------- prep: bake nonlin frags + sconv A-frags into ws
__global__ void scnn_prep(const float* __restrict__ sft, const float* __restrict__ isft,
                          const float* __restrict__ w1, const float* __restrict__ w2,
                          const float* __restrict__ w3, const float* __restrict__ w4,
                          const float* __restrict__ w5, const float* __restrict__ w6,
                          const float* __restrict__ w7, const float* __restrict__ w8,
                          const float* __restrict__ w9, u32* __restrict__ wsbuf) {
  const int gid = blockIdx.x * 256 + threadIdx.x;
  if (gid < 3584) {  // A1 frags (isft)
    const int f = gid >> 8, r = gid & 255, ln = r >> 2, wd = r & 3;
    const int mt = f >> 1, kt = f & 1;
    const int d = 16 * mt + (ln & 15);
    const int c = 32 * kt + 8 * (ln >> 4) + 2 * wd;
    const float v0 = (d < 100 && c < 45) ? isft[d * 45 + c] : 0.f;
    const float v1 = (d < 100 && c + 1 < 45) ? isft[d * 45 + c + 1] : 0.f;
    wsbuf[gid] = pk2rne(v0, v1);
  } else if (gid < WS_FRAG_U32) {  // A2 frags (sft)
    const int e = gid - 3584;
    const int f = e >> 8, r = e & 255, ln = r >> 2, wd = r & 3;
    const int mt = f >> 2, kt = f & 3;
    const int c = 16 * mt + (ln & 15);
    const int d = 32 * kt + 8 * (ln >> 4) + 2 * wd;
    const float v0 = (c < 45 && d < 100) ? sft[c * 100 + d] : 0.f;
    const float v1 = (c < 45 && d + 1 < 100) ? sft[c * 100 + d + 1] : 0.f;
    wsbuf[gid] = pk2rne(v0, v1);
  } else if (gid < WS_FRAG_U32 + WS_AFRAG_U32) {  // sconv A-frags, lfac folded
    const int e = gid - WS_FRAG_U32;
    const int frag = e >> 8, r = e & 255, ln = r >> 2, wd = r & 3;
    const float* src; int O, I, Mt, Kt, off;
    if (frag < 5)        { src = w1; O = 16;  I = 4;   Mt = 1; Kt = 1; off = 0;   }
    else if (frag < 15)  { src = w2; O = 32;  I = 16;  Mt = 2; Kt = 1; off = 5;   }
    else if (frag < 35)  { src = w3; O = 64;  I = 32;  Mt = 4; Kt = 1; off = 15;  }
    else if (frag < 115) { src = w4; O = 128; I = 64;  Mt = 8; Kt = 2; off = 35;  }
    else if (frag < 195) { src = w5; O = 64;  I = 128; Mt = 4; Kt = 4; off = 115; }
    else if (frag < 235) { src = w6; O = 32;  I = 128; Mt = 2; Kt = 4; off = 195; }
    else if (frag < 245) { src = w7; O = 16;  I = 64;  Mt = 1; Kt = 2; off = 235; }
    else                 { src = w8; O = 16;  I = 32;  Mt = 1; Kt = 1; off = 245; }
    const int fl = frag - off;
    const int l = fl / (Mt * Kt), rem = fl % (Mt * Kt);
    const int mt = rem / Kt, kt = rem % Kt;
    const int o = 16 * mt + (ln & 15);
    const int i0 = 32 * kt + 8 * (ln >> 4) + 2 * wd;
    const float lf = lfac_of(l);
    const float v0 = (i0 < I) ? src[(o * I + i0) * 5 + l] * lf : 0.f;
    const float v1 = (i0 + 1 < I) ? src[(o * I + i0 + 1) * 5 + l] * lf : 0.f;
    wsbuf[gid] = pk2rne(v0, v1);
  }
  (void)w9;
}

// ---------------- main fused kernel
template <bool TW>
__global__ __launch_bounds__(256, 3) void scnn_mfma(
    const float* __restrict__ x, const float* __restrict__ sft, const float* __restrict__ isft,
    const float* __restrict__ w1, const float* __restrict__ w2, const float* __restrict__ w3,
    const float* __restrict__ w4, const float* __restrict__ w5, const float* __restrict__ w6,
    const float* __restrict__ w7, const float* __restrict__ w8, const float* __restrict__ w9,
    const u32* __restrict__ wsbuf, float* __restrict__ out) {
  __shared__ __align__(16) char smem[NPAIRS * PRB];
  const int tid = threadIdx.x, lane = tid & 63, wid = tid >> 6, b = blockIdx.x;
  const uint4* p2 = TW ? ((const uint4*)wsbuf) + 14 * 64 : nullptr;
  const uint4* afrB = TW ? ((const uint4*)wsbuf) + (WS_FRAG_U32 / 4) : nullptr;

  Frags F;
  if constexpr (TW) {
    const uint4* p1 = (const uint4*)wsbuf;
#pragma unroll
    for (int f = 0; f < 14; ++f)
      F.a1[f / 2][f % 2] = __builtin_bit_cast(f16x8, p1[f * 64 + lane]);
  } else {
    const int i15 = lane & 15, g = lane >> 4;
#pragma unroll
    for (int mt = 0; mt < 7; ++mt)
#pragma unroll
      for (int kt = 0; kt < 2; ++kt) {
        const int d = 16 * mt + i15;
        f16x8 v;
#pragma unroll
        for (int j = 0; j < 8; ++j) {
          const int c = 32 * kt + 8 * g + j;
          v[j] = (half_t)((d < 100 && c < 45) ? isft[d * 45 + c] : 0.f);
        }
        F.a1[mt][kt] = v;
      }
  }

  // zero the ENTIRE buffer (K-padded MFMA B-reads must see finite zeros)
  for (int idx = tid; idx < (NPAIRS * PRB) / 4; idx += 256)
    ((u32*)smem)[idx] = 0u;
  __syncthreads();
  // stage x [4,45] -> rows 0..3 (paired layout)
  if (tid < 192) {
    const int r = tid / 48, c = tid % 48;
    const float v = (c < 45) ? x[b * 180 + r * 45 + c] : 0.f;
    *(half_t*)(smem + (r >> 1) * PRB + c * 4 + (r & 1) * 2) = (half_t)v;
  }
  __syncthreads();

  if constexpr (TW) {
    sconv_mfma<16, 4, 4, true>(afrB + 0 * 64, smem, lane, wid, 0, 0, 0);
    nonlin_tiles<TW>(F, p2, sft, smem, lane, wid, 1, 1, 0, 0, E1R, E1R);
    __syncthreads();
    sconv_mfma<32, 16, 16, false>(afrB + 5 * 64, smem, lane, wid, E1R, E1R, 0);
    nonlin_tiles<TW>(F, p2, sft, smem, lane, wid, 2, 2, 0, 0, E2R, E2R);
    __syncthreads();
    sconv_mfma<64, 32, 32, false>(afrB + 15 * 64, smem, lane, wid, E2R, E2R, 0);
    nonlin_tiles<TW>(F, p2, sft, smem, lane, wid, 4, 4, 0, 0, E3R, E3R);
    __syncthreads();
    sconv_mfma<128, 64, 64, false>(afrB + 35 * 64, smem, lane, wid, E3R, E3R, 0);
    nonlin_tiles<TW>(F, p2, sft, smem, lane, wid, 8, 8, 0, 0, 0, 0);
    __syncthreads();
    sconv_mfma<64, 128, 128, true>(afrB + 115 * 64, smem, lane, wid, 0, 0, 0);
    nonlin_tiles<TW>(F, p2, sft, smem, lane, wid, 8, 4, 0, E3R, 0, E3R);
    __syncthreads();
    sconv_mfma<32, 128, 64, true>(afrB + 195 * 64, smem, lane, wid, 0, E3R, 0);
    nonlin_tiles<TW>(F, p2, sft, smem, lane, wid, 4, 2, 0, E2R, 0, E2R);
    __syncthreads();
    sconv_mfma<16, 64, 32, true>(afrB + 235 * 64, smem, lane, wid, 0, E2R, 0);
    nonlin_tiles<TW>(F, p2, sft, smem, lane, wid, 2, 1, 0, E1R, 0, E1R);
    __syncthreads();
    sconv_mfma<16, 32, 16, true>(afrB + 245 * 64, smem, lane, wid, 0, E1R, 0);
    nonlin_tiles<TW>(F, p2, sft, smem, lane, wid, 1, 1, 0, 0, 0, 0);
    __syncthreads();
  } else {
    sconv_layer<16, 4, 4, 3, 4>(w1, smem, tid, 0, 0, 0);
    nonlin_tiles<TW>(F, p2, sft, smem, lane, wid, 1, 1, 0, 0, E1R, E1R);
    __syncthreads();
    sconv_layer<32, 16, 16, 2, 4>(w2, smem, tid, E1R, E1R, 0);
    nonlin_tiles<TW>(F, p2, sft, smem, lane, wid, 2, 2, 0, 0, E2R, E2R);
    __syncthreads();
    sconv_layer<64, 32, 32, 2, 2>(w3, smem, tid, E2R, E2R, 0);
    nonlin_tiles<TW>(F, p2, sft, smem, lane, wid, 4, 4, 0, 0, E3R, E3R);
    __syncthreads();
    sconv_layer<128, 64, 64, 2, 1>(w4, smem, tid, E3R, E3R, 0);
    nonlin_tiles<TW>(F, p2, sft, smem, lane, wid, 8, 8, 0, 0, 0, 0);
    __syncthreads();
    sconv_layer<64, 128, 128, 2, 2>(w5, smem, tid, 0, 0, 0);
    nonlin_tiles<TW>(F, p2, sft, smem, lane, wid, 8, 4, 0, E3R, 0, E3R);
    __syncthreads();
    sconv_layer<32, 128, 64, 2, 4>(w6, smem, tid, 0, E3R, 0);
    nonlin_tiles<TW>(F, p2, sft, smem, lane, wid, 4, 2, 0, E2R, 0, E2R);
    __syncthreads();
    sconv_layer<16, 64, 32, 3, 4>(w7, smem, tid, 0, E2R, 0);
    nonlin_tiles<TW>(F, p2, sft, smem, lane, wid, 2, 1, 0, E1R, 0, E1R);
    __syncthreads();
    sconv_layer<16, 32, 16, 3, 4>(w8, smem, tid, 0, E1R, 0);
    nonlin_tiles<TW>(F, p2, sft, smem, lane, wid, 1, 1, 0, 0, 0, 0);
    __syncthreads();
  }

  // final sconv: O=1, I=16 (d4 rows 0..15) -> out[b,c] fp32
  if (tid < 45) {
    const int c = tid, l = l_of(c);
    float acc = 0.f;
#pragma unroll
    for (int i = 0; i < 16; ++i)
      acc += w9[i * 5 + l] *
             (float)(*(const half_t*)(smem + (i >> 1) * PRB + c * 4 + (i & 1) * 2));
    out[b * 45 + c] = acc * lfac_of(l);
  }
}

extern "C" void kernel_launch(void* const* d_in, const int* in_sizes, int n_in,
                              void* d_out, int out_size, void* d_ws, size_t ws_size,
                              hipStream_t stream) {
  (void)n_in; (void)out_size;
  const float* x    = (const float*)d_in[0];
  const float* sft  = (const float*)d_in[1];
  const float* isft = (const float*)d_in[2];
  const float* w1 = (const float*)d_in[3];
  const float* w2 = (const float*)d_in[4];
  const float* w3 = (const float*)d_in[5];
  const float* w4 = (const float*)d_in[6];
  const float* w5 = (const float*)d_in[7];
  const float* w6 = (const float*)d_in[8];
  const float* w7 = (const float*)d_in[9];
  const float* w8 = (const float*)d_in[10];
  const float* w9 = (const float*)d_in[11];
  float* out = (float*)d_out;

  const int batch = in_sizes[0] / 180;  // 16384

  if (ws_size >= (size_t)WS_NEEDED) {
    u32* wsbuf = (u32*)d_ws;
    const int prepN = WS_FRAG_U32 + WS_AFRAG_U32;
    hipLaunchKernelGGL(scnn_prep, dim3((prepN + 255) / 256), dim3(256), 0, stream,
                       sft, isft, w1, w2, w3, w4, w5, w6, w7, w8, w9, wsbuf);
    hipLaunchKernelGGL((scnn_mfma<true>), dim3(batch), dim3(256), 0, stream,
                       x, sft, isft, w1, w2, w3, w4, w5, w6, w7, w8, w9, wsbuf, out);
  } else {
    hipLaunchKernelGGL((scnn_mfma<false>), dim3(batch), dim3(256), 0, stream,
                       x, sft, isft, w1, w2, w3, w4, w5, w6, w7, w8, w9,
                       (const u32*)nullptr, out);
  }
}